// Round 1
// baseline (907.330 us; speedup 1.0000x reference)
//
#include <hip/hip_runtime.h>
#include <hip/hip_bf16.h>
#include <stdint.h>

typedef unsigned short u16;
typedef __bf16 bf16x8 __attribute__((ext_vector_type(8)));
typedef u16 u16x8 __attribute__((ext_vector_type(8)));
typedef float f32x4 __attribute__((ext_vector_type(4)));

#define DEV __device__ __forceinline__

DEV u16 f2bf(float f) {
  uint32_t u = __builtin_bit_cast(uint32_t, f);
  return (u16)((u + 0x7FFFu + ((u >> 16) & 1u)) >> 16);
}
DEV float bf2f(u16 h) { return __builtin_bit_cast(float, (uint32_t)h << 16); }

DEV void gload_lds16(const void* g, void* l) {
  __builtin_amdgcn_global_load_lds((const __attribute__((address_space(1))) uint32_t*)g,
                                   (__attribute__((address_space(3))) uint32_t*)l, 16, 0, 0);
}

// ---------------- elementwise f32 -> bf16 cast ----------------
__global__ void cvt_bf16(const float* __restrict__ in, u16* __restrict__ out, int n) {
  int i = (blockIdx.x * 256 + threadIdx.x) * 8;
  if (i >= n) return;
  const float4* p = reinterpret_cast<const float4*>(in + i);
  float4 a = p[0], b = p[1];
  u16x8 o;
  o[0] = f2bf(a.x); o[1] = f2bf(a.y); o[2] = f2bf(a.z); o[3] = f2bf(a.w);
  o[4] = f2bf(b.x); o[5] = f2bf(b.y); o[6] = f2bf(b.z); o[7] = f2bf(b.w);
  *reinterpret_cast<u16x8*>(out + i) = o;
}

// ---------------- RoPE cos/sin table (S=2048, 64 pairs) ----------------
__global__ void rope_table(float* __restrict__ ct, float* __restrict__ st) {
  int i = blockIdx.x * 256 + threadIdx.x;  // S*64 total
  int s = i >> 6, d = i & 63;
  float invf = powf(10000.0f, -(float)d * (1.0f / 64.0f));
  float ang = (float)s * invf;
  ct[i] = cosf(ang);
  st[i] = sinf(ang);
}

// ---------------- RoPE applied in-place on bf16 qkv (Q heads 0..31, K heads 32..39) ----------------
__global__ void rope_apply(u16* __restrict__ qkv, const float* __restrict__ ct, const float* __restrict__ st) {
  int idx = blockIdx.x * 256 + threadIdx.x;  // 4096 rows * 40 heads * 8 groups
  int grp = idx & 7;
  int head = (idx >> 3) % 40;
  int row = idx / 320;
  int s = row & 2047;
  size_t f0 = head < 32 ? (size_t)head * 128 : (size_t)4096 + (size_t)(head - 32) * 128;
  u16* p = qkv + (size_t)row * 6144 + f0 + grp * 8;
  u16x8 a = *reinterpret_cast<const u16x8*>(p);
  u16x8 b = *reinterpret_cast<const u16x8*>(p + 64);
  const float4* cp = reinterpret_cast<const float4*>(ct + s * 64 + grp * 8);
  const float4* sp = reinterpret_cast<const float4*>(st + s * 64 + grp * 8);
  float4 c0 = cp[0], c1 = cp[1], s0 = sp[0], s1 = sp[1];
  float cc[8] = {c0.x, c0.y, c0.z, c0.w, c1.x, c1.y, c1.z, c1.w};
  float ss[8] = {s0.x, s0.y, s0.z, s0.w, s1.x, s1.y, s1.z, s1.w};
  u16x8 o1, o2;
#pragma unroll
  for (int i = 0; i < 8; i++) {
    float x1 = bf2f(a[i]), x2 = bf2f(b[i]);
    o1[i] = f2bf(x1 * cc[i] - x2 * ss[i]);
    o2[i] = f2bf(x2 * cc[i] + x1 * ss[i]);
  }
  *reinterpret_cast<u16x8*>(p) = o1;
  *reinterpret_cast<u16x8*>(p + 64) = o2;
}

// ---------------- GEMM: C[M][N] = A[M][K] * B[N][K]^T, bf16 in, OutT out ----------------
DEV void store_c(float* C, size_t idx, float v) { C[idx] = v; }
DEV void store_c(u16* C, size_t idx, float v) { C[idx] = f2bf(v); }

template <typename OutT>
__global__ __launch_bounds__(256) void gemm_bt(const u16* __restrict__ A, const u16* __restrict__ B,
                                               OutT* __restrict__ C, int M, int N, int K) {
  __shared__ __align__(16) u16 As[128 * 32];
  __shared__ __align__(16) u16 Bs[128 * 32];
  const int tid = threadIdx.x;
  const int wave = tid >> 6, lane = tid & 63;
  const int l15 = lane & 15, l4 = lane >> 4;
  const int row0 = blockIdx.y * 128, col0 = blockIdx.x * 128;
  const int wr = wave >> 1, wc = wave & 1;
  const int sr = tid >> 2;       // staging row 0..63
  const int sc = (tid & 3) * 8;  // staging col (elements)
  f32x4 acc[4][4] = {};

  const u16* gA = A + (size_t)(row0 + sr) * K + sc;
  const u16* gB = B + (size_t)(col0 + sr) * K + sc;
  char* ldsA = ((char*)As) + wave * 1024;
  char* ldsB = ((char*)Bs) + wave * 1024;

  for (int kt = 0; kt < K; kt += 32) {
    gload_lds16(gA + kt, ldsA);
    gload_lds16(gA + (size_t)64 * K + kt, ldsA + 4096);
    gload_lds16(gB + kt, ldsB);
    gload_lds16(gB + (size_t)64 * K + kt, ldsB + 4096);
    asm volatile("s_waitcnt vmcnt(0)" ::: "memory");
    __syncthreads();
    bf16x8 af[4], bfr[4];
#pragma unroll
    for (int m = 0; m < 4; m++)
      af[m] = *reinterpret_cast<const bf16x8*>(As + (wr * 64 + m * 16 + l15) * 32 + l4 * 8);
#pragma unroll
    for (int n = 0; n < 4; n++)
      bfr[n] = *reinterpret_cast<const bf16x8*>(Bs + (wc * 64 + n * 16 + l15) * 32 + l4 * 8);
#pragma unroll
    for (int m = 0; m < 4; m++)
#pragma unroll
      for (int n = 0; n < 4; n++)
        acc[m][n] = __builtin_amdgcn_mfma_f32_16x16x32_bf16(af[m], bfr[n], acc[m][n], 0, 0, 0);
    __syncthreads();
  }
#pragma unroll
  for (int m = 0; m < 4; m++)
#pragma unroll
    for (int n = 0; n < 4; n++)
#pragma unroll
      for (int r = 0; r < 4; r++) {
        size_t row = (size_t)row0 + wr * 64 + m * 16 + l4 * 4 + r;
        size_t col = (size_t)col0 + wc * 64 + n * 16 + l15;
        store_c(C, row * (size_t)N + col, acc[m][n][r]);
      }
}

// ---------------- causal GQA flash attention ----------------
// qkv: [B*S][6144] bf16 (Q 0..4095 by head, K 4096+kvh*128, V 5120+kvh*128), rope already applied
// out: [B*S][4096] bf16, col = h*128 + d
__global__ __launch_bounds__(256) void attn_fwd(const u16* __restrict__ qkv, u16* __restrict__ out) {
  constexpr int S = 2048, F = 6144, E = 4096;
  __shared__ __align__(16) u16 Kt[64 * 128];     // [kv][d], chunk-swizzled
  __shared__ __align__(16) u16 Vt[128 * 64];     // [d][kv], swizzled
  __shared__ __align__(16) u16 Pl[4][16 * 64];   // per-wave P, swizzled

  const int tid = threadIdx.x;
  const int wave = tid >> 6, lane = tid & 63;
  const int l15 = lane & 15, l4 = lane >> 4;
  const int q0 = blockIdx.x * 64;
  const int b = blockIdx.y >> 5, h = blockIdx.y & 31, kvh = h >> 2;
  const size_t rowB = (size_t)b * S;
  const float scale = 0.08838834764831845f;  // 1/sqrt(128)

  bf16x8 qf[4];
  {
    const u16* qp = qkv + (rowB + q0 + wave * 16 + l15) * F + h * 128;
#pragma unroll
    for (int kk = 0; kk < 4; kk++) qf[kk] = *reinterpret_cast<const bf16x8*>(qp + kk * 32 + l4 * 8);
  }

  f32x4 acco[8] = {};
  float m_r[4], l_r[4];
#pragma unroll
  for (int r = 0; r < 4; r++) { m_r[r] = -1e30f; l_r[r] = 0.f; }

  const int sgn = tid >> 4;  // 0..15
  const int sgc = tid & 15;  // 16B chunk
  for (int j = 0; j <= blockIdx.x; j++) {
    // stage K tile: pre-swizzled global source -> linear LDS (global_load_lds)
#pragma unroll
    for (int p = 0; p < 4; p++) {
      int n = p * 16 + sgn;
      int kc = sgc ^ (n & 7);
      const u16* g = qkv + (rowB + j * 64 + n) * F + 4096 + kvh * 128 + kc * 8;
      gload_lds16(g, ((char*)Kt) + p * 4096 + wave * 1024);
    }
    // stage V transposed: reg -> swizzled LDS
#pragma unroll
    for (int p = 0; p < 4; p++) {
      int kv = p * 16 + sgn;
      int d0 = sgc * 8;
      u16x8 v = *reinterpret_cast<const u16x8*>(qkv + (rowB + j * 64 + kv) * F + 5120 + kvh * 128 + d0);
#pragma unroll
      for (int i = 0; i < 8; i++) {
        int d = d0 + i;
        int sw = ((d & 7) ^ ((d >> 3) & 7)) << 4;
        *(u16*)(((char*)Vt) + d * 128 + ((kv * 2) ^ sw)) = v[i];
      }
    }
    asm volatile("s_waitcnt vmcnt(0)" ::: "memory");
    __syncthreads();

    // S = Q K^T  (16 q-rows x 64 kv)
    f32x4 accs[4] = {};
#pragma unroll
    for (int ns = 0; ns < 4; ns++) {
      int n = ns * 16 + l15;
#pragma unroll
      for (int kk = 0; kk < 4; kk++) {
        bf16x8 kf = *reinterpret_cast<const bf16x8*>(((char*)Kt) + n * 256 + (((kk * 4 + l4) ^ (n & 7)) << 4));
        accs[ns] = __builtin_amdgcn_mfma_f32_16x16x32_bf16(qf[kk], kf, accs[ns], 0, 0, 0);
      }
    }
    // scale + causal mask (only the diagonal tile needs masking)
    const int qrow = q0 + wave * 16 + l4 * 4;  // + r
    const int kvc = j * 64 + l15;              // + ns*16
    if (j == blockIdx.x) {
#pragma unroll
      for (int ns = 0; ns < 4; ns++)
#pragma unroll
        for (int r = 0; r < 4; r++)
          accs[ns][r] = (kvc + ns * 16 > qrow + r) ? -1e30f : accs[ns][r] * scale;
    } else {
#pragma unroll
      for (int ns = 0; ns < 4; ns++)
#pragma unroll
        for (int r = 0; r < 4; r++) accs[ns][r] *= scale;
    }
    // online softmax (rows live in 16-lane groups)
    float fr[4], mn[4];
#pragma unroll
    for (int r = 0; r < 4; r++) {
      float tm = fmaxf(fmaxf(accs[0][r], accs[1][r]), fmaxf(accs[2][r], accs[3][r]));
      tm = fmaxf(tm, __shfl_xor(tm, 1));
      tm = fmaxf(tm, __shfl_xor(tm, 2));
      tm = fmaxf(tm, __shfl_xor(tm, 4));
      tm = fmaxf(tm, __shfl_xor(tm, 8));
      float m2 = fmaxf(m_r[r], tm);
      fr[r] = __expf(m_r[r] - m2);
      mn[r] = m2;
      m_r[r] = m2;
    }
    float ps[4] = {0.f, 0.f, 0.f, 0.f};
#pragma unroll
    for (int ns = 0; ns < 4; ns++)
#pragma unroll
      for (int r = 0; r < 4; r++) {
        float p = __expf(accs[ns][r] - mn[r]);
        ps[r] += p;
        int row = l4 * 4 + r;
        *(u16*)(((char*)&Pl[wave][0]) + row * 128 + (((ns * 16 + l15) * 2) ^ ((row & 7) << 4))) = f2bf(p);
      }
#pragma unroll
    for (int r = 0; r < 4; r++) {
      float s2 = ps[r];
      s2 += __shfl_xor(s2, 1); s2 += __shfl_xor(s2, 2); s2 += __shfl_xor(s2, 4); s2 += __shfl_xor(s2, 8);
      l_r[r] = l_r[r] * fr[r] + s2;
    }
#pragma unroll
    for (int ns = 0; ns < 8; ns++)
#pragma unroll
      for (int r = 0; r < 4; r++) acco[ns][r] *= fr[r];
    // O += P V
#pragma unroll
    for (int kk = 0; kk < 2; kk++) {
      int row = l15;
      int k8 = kk * 4 + l4;
      bf16x8 pf = *reinterpret_cast<const bf16x8*>(((char*)&Pl[wave][0]) + row * 128 + (((k8) ^ (row & 7)) << 4));
#pragma unroll
      for (int ns = 0; ns < 8; ns++) {
        int d = ns * 16 + l15;
        int sw = (d & 7) ^ ((d >> 3) & 7);
        bf16x8 vf = *reinterpret_cast<const bf16x8*>(((char*)Vt) + d * 128 + (((k8) ^ sw) << 4));
        acco[ns] = __builtin_amdgcn_mfma_f32_16x16x32_bf16(pf, vf, acco[ns], 0, 0, 0);
      }
    }
    __syncthreads();
  }
  // epilogue: normalize + store bf16
#pragma unroll
  for (int r = 0; r < 4; r++) {
    float inv = 1.f / l_r[r];
    size_t row = rowB + q0 + wave * 16 + l4 * 4 + r;
#pragma unroll
    for (int ns = 0; ns < 8; ns++)
      out[row * E + h * 128 + ns * 16 + l15] = f2bf(acco[ns][r] * inv);
  }
}

extern "C" void kernel_launch(void* const* d_in, const int* in_sizes, int n_in,
                              void* d_out, int out_size, void* d_ws, size_t ws_size,
                              hipStream_t stream) {
  const float* x = (const float*)d_in[0];
  const float* w_in = (const float*)d_in[1];
  const float* w_out = (const float*)d_in[2];
  float* out = (float*)d_out;
  char* ws = (char*)d_ws;

  // workspace layout (total ~169 MB)
  u16* xb = (u16*)(ws);                                   // 33,554,432 B (reused as attn out)
  u16* wib = (u16*)(ws + 33554432ull);                    // 50,331,648 B
  u16* wob = (u16*)(ws + 83886080ull);                    // 33,554,432 B
  u16* qkvb = (u16*)(ws + 117440512ull);                  // 50,331,648 B
  float* ct = (float*)(ws + 167772160ull);                // 524,288 B
  float* st = ct + 2048 * 64;                             // 524,288 B
  u16* attnb = xb;

  cvt_bf16<<<8192, 256, 0, stream>>>(x, xb, 16777216);
  cvt_bf16<<<12288, 256, 0, stream>>>(w_in, wib, 25165824);
  cvt_bf16<<<8192, 256, 0, stream>>>(w_out, wob, 16777216);
  rope_table<<<512, 256, 0, stream>>>(ct, st);
  gemm_bt<u16><<<dim3(48, 32), 256, 0, stream>>>(xb, wib, qkvb, 4096, 6144, 4096);
  rope_apply<<<5120, 256, 0, stream>>>(qkvb, ct, st);
  attn_fwd<<<dim3(32, 64), 256, 0, stream>>>(qkvb, attnb);
  gemm_bt<float><<<dim3(32, 32), 256, 0, stream>>>(attnb, wob, out, 4096, 4096, 4096);
}

// Round 2
// 728.607 us; speedup vs baseline: 1.2453x; 1.2453x over previous
//
#include <hip/hip_runtime.h>
#include <hip/hip_bf16.h>
#include <stdint.h>

typedef unsigned short u16;
typedef __bf16 bf16x8 __attribute__((ext_vector_type(8)));
typedef u16 u16x8 __attribute__((ext_vector_type(8)));
typedef float f32x4 __attribute__((ext_vector_type(4)));

#define DEV __device__ __forceinline__

DEV u16 f2bf(float f) {
  uint32_t u = __builtin_bit_cast(uint32_t, f);
  return (u16)((u + 0x7FFFu + ((u >> 16) & 1u)) >> 16);
}
DEV float bf2f(u16 h) { return __builtin_bit_cast(float, (uint32_t)h << 16); }

DEV void gload_lds16(const void* g, void* l) {
  __builtin_amdgcn_global_load_lds((const __attribute__((address_space(1))) uint32_t*)g,
                                   (__attribute__((address_space(3))) uint32_t*)l, 16, 0, 0);
}

// ---------------- elementwise f32 -> bf16 cast ----------------
__global__ void cvt_bf16(const float* __restrict__ in, u16* __restrict__ out, int n) {
  int i = (blockIdx.x * 256 + threadIdx.x) * 8;
  if (i >= n) return;
  const float4* p = reinterpret_cast<const float4*>(in + i);
  float4 a = p[0], b = p[1];
  u16x8 o;
  o[0] = f2bf(a.x); o[1] = f2bf(a.y); o[2] = f2bf(a.z); o[3] = f2bf(a.w);
  o[4] = f2bf(b.x); o[5] = f2bf(b.y); o[6] = f2bf(b.z); o[7] = f2bf(b.w);
  *reinterpret_cast<u16x8*>(out + i) = o;
}

// ---------------- RoPE cos/sin table (S=2048, 64 pairs) ----------------
__global__ void rope_table(float* __restrict__ ct, float* __restrict__ st) {
  int i = blockIdx.x * 256 + threadIdx.x;  // S*64 total
  int s = i >> 6, d = i & 63;
  float invf = powf(10000.0f, -(float)d * (1.0f / 64.0f));
  float ang = (float)s * invf;
  ct[i] = cosf(ang);
  st[i] = sinf(ang);
}

// ---------------- RoPE applied in-place on bf16 qkv (Q heads 0..31, K heads 32..39) ----------------
__global__ void rope_apply(u16* __restrict__ qkv, const float* __restrict__ ct, const float* __restrict__ st) {
  int idx = blockIdx.x * 256 + threadIdx.x;  // 4096 rows * 40 heads * 8 groups
  int grp = idx & 7;
  int head = (idx >> 3) % 40;
  int row = idx / 320;
  int s = row & 2047;
  size_t f0 = head < 32 ? (size_t)head * 128 : (size_t)4096 + (size_t)(head - 32) * 128;
  u16* p = qkv + (size_t)row * 6144 + f0 + grp * 8;
  u16x8 a = *reinterpret_cast<const u16x8*>(p);
  u16x8 b = *reinterpret_cast<const u16x8*>(p + 64);
  const float4* cp = reinterpret_cast<const float4*>(ct + s * 64 + grp * 8);
  const float4* sp = reinterpret_cast<const float4*>(st + s * 64 + grp * 8);
  float4 c0 = cp[0], c1 = cp[1], s0 = sp[0], s1 = sp[1];
  float cc[8] = {c0.x, c0.y, c0.z, c0.w, c1.x, c1.y, c1.z, c1.w};
  float ss[8] = {s0.x, s0.y, s0.z, s0.w, s1.x, s1.y, s1.z, s1.w};
  u16x8 o1, o2;
#pragma unroll
  for (int i = 0; i < 8; i++) {
    float x1 = bf2f(a[i]), x2 = bf2f(b[i]);
    o1[i] = f2bf(x1 * cc[i] - x2 * ss[i]);
    o2[i] = f2bf(x2 * cc[i] + x1 * ss[i]);
  }
  *reinterpret_cast<u16x8*>(p) = o1;
  *reinterpret_cast<u16x8*>(p + 64) = o2;
}

// ---------------- V^T tile image prep ----------------
// For each (b,kvh,j): build a 16KB LDS image of V^T (d-major, kv contiguous, XOR-swizzled
// 16B chunks) so attn can stage it with linear global_load_lds.
// element (d, kv) at byte d*128 + (((kv>>3) ^ (d&7))<<4) + (kv&7)*2
__global__ void prep_vt(const u16* __restrict__ qkv, u16* __restrict__ vtg) {
  int id = blockIdx.x;  // (b*8+kvh)*32 + j
  int j = id & 31, kvh = (id >> 5) & 7, b = id >> 8;
  const int tid = threadIdx.x;
  const size_t rowB = (size_t)b * 2048;
  u16* img = vtg + (size_t)id * 8192;
#pragma unroll
  for (int p = 0; p < 4; p++) {
    int lin = p * 256 + tid;  // 0..1023 chunk id
    int d = lin >> 3, c = lin & 7;
    const u16* src = qkv + (rowB + j * 64 + c * 8) * 6144 + 5120 + kvh * 128 + d;
    u16x8 v;
#pragma unroll
    for (int i = 0; i < 8; i++) v[i] = src[(size_t)i * 6144];
    *reinterpret_cast<u16x8*>(img + d * 64 + ((c ^ (d & 7)) << 3)) = v;
  }
}

// ---------------- GEMM: C[M][N] = A[M][K] * B[N][K]^T, bf16 in, OutT out ----------------
DEV void store_c(float* C, size_t idx, float v) { C[idx] = v; }
DEV void store_c(u16* C, size_t idx, float v) { C[idx] = f2bf(v); }

template <typename OutT>
__global__ __launch_bounds__(256) void gemm_bt(const u16* __restrict__ A, const u16* __restrict__ B,
                                               OutT* __restrict__ C, int M, int N, int K) {
  __shared__ __align__(16) u16 As[128 * 32];
  __shared__ __align__(16) u16 Bs[128 * 32];
  const int tid = threadIdx.x;
  const int wave = tid >> 6, lane = tid & 63;
  const int l15 = lane & 15, l4 = lane >> 4;
  const int row0 = blockIdx.y * 128, col0 = blockIdx.x * 128;
  const int wr = wave >> 1, wc = wave & 1;
  const int sr = tid >> 2;       // staging row 0..63
  const int sc = (tid & 3) * 8;  // staging col (elements)
  f32x4 acc[4][4] = {};

  const u16* gA = A + (size_t)(row0 + sr) * K + sc;
  const u16* gB = B + (size_t)(col0 + sr) * K + sc;
  char* ldsA = ((char*)As) + wave * 1024;
  char* ldsB = ((char*)Bs) + wave * 1024;

  for (int kt = 0; kt < K; kt += 32) {
    gload_lds16(gA + kt, ldsA);
    gload_lds16(gA + (size_t)64 * K + kt, ldsA + 4096);
    gload_lds16(gB + kt, ldsB);
    gload_lds16(gB + (size_t)64 * K + kt, ldsB + 4096);
    asm volatile("s_waitcnt vmcnt(0)" ::: "memory");
    __syncthreads();
    bf16x8 af[4], bfr[4];
#pragma unroll
    for (int m = 0; m < 4; m++)
      af[m] = *reinterpret_cast<const bf16x8*>(As + (wr * 64 + m * 16 + l15) * 32 + l4 * 8);
#pragma unroll
    for (int n = 0; n < 4; n++)
      bfr[n] = *reinterpret_cast<const bf16x8*>(Bs + (wc * 64 + n * 16 + l15) * 32 + l4 * 8);
#pragma unroll
    for (int m = 0; m < 4; m++)
#pragma unroll
      for (int n = 0; n < 4; n++)
        acc[m][n] = __builtin_amdgcn_mfma_f32_16x16x32_bf16(af[m], bfr[n], acc[m][n], 0, 0, 0);
    __syncthreads();
  }
#pragma unroll
  for (int m = 0; m < 4; m++)
#pragma unroll
    for (int n = 0; n < 4; n++)
#pragma unroll
      for (int r = 0; r < 4; r++) {
        size_t row = (size_t)row0 + wr * 64 + m * 16 + l4 * 4 + r;
        size_t col = (size_t)col0 + wc * 64 + n * 16 + l15;
        store_c(C, row * (size_t)N + col, acc[m][n][r]);
      }
}

// ---------------- causal GQA flash attention, v2 ----------------
// 4 waves x 32 q-rows = 128 q-rows/block. KVBLK=64. Double-buffered K/V staging via
// global_load_lds (K: pre-swizzled source from qkv; V: contiguous from prep_vt image).
// Paired q-tiles (t, 15-t) -> 512 equal-work blocks (2/CU). exp2-domain online softmax
// with defer-max (THR=8). P via per-wave swizzled LDS round-trip.
__global__ __launch_bounds__(256, 2) void attn_fwd(const u16* __restrict__ qkv,
                                                   const u16* __restrict__ vtg,
                                                   u16* __restrict__ out) {
  constexpr int S = 2048, F = 6144, E = 4096;
  __shared__ __align__(16) u16 Kt[2 * 8192];
  __shared__ __align__(16) u16 Vt[2 * 8192];
  __shared__ __align__(16) u16 Pl[4 * 2048];

  const int tid = threadIdx.x;
  const int w = tid >> 6, lane = tid & 63;
  const int l15 = lane & 15, l4 = lane >> 4;
  const int pair = blockIdx.x;  // 0..7
  const int b = blockIdx.y >> 5, h = blockIdx.y & 31, kvh = h >> 2;
  const size_t rowB = (size_t)b * S;
  const float sc = 0.08838834764831845f * 1.4426950408889634f;  // 1/sqrt(128) * log2(e)
  const int sgn = tid >> 4, sgc = tid & 15;
  char* PlW = ((char*)Pl) + w * 4096;
  const size_t vtb = (size_t)(b * 8 + kvh) * 32 * 8192;

  auto stage = [&](int j, int buf) {
    char* kd = ((char*)Kt) + buf * 16384 + w * 1024;
    char* vd = ((char*)Vt) + buf * 16384 + w * 1024;
    const u16* vs = vtg + vtb + (size_t)j * 8192 + tid * 8;
#pragma unroll
    for (int p = 0; p < 4; p++) {
      int n = p * 16 + sgn;
      const u16* g = qkv + (rowB + j * 64 + n) * F + 4096 + kvh * 128 + (sgc ^ (n & 7)) * 8;
      gload_lds16(g, kd + p * 4096);
      gload_lds16(vs + p * 2048, vd + p * 4096);
    }
  };

  for (int half = 0; half < 2; ++half) {
    const int t = half ? 15 - pair : pair;
    const int nt = 2 * t + 2;
    const int r0 = t * 128;

    // Q fragments: 32 rows x 128 d per wave
    bf16x8 qf[2][4];
    {
      const u16* qp = qkv + (rowB + r0 + w * 32 + l15) * F + h * 128 + l4 * 8;
#pragma unroll
      for (int m = 0; m < 2; m++)
#pragma unroll
        for (int kk = 0; kk < 4; kk++)
          qf[m][kk] = *reinterpret_cast<const bf16x8*>(qp + (size_t)m * 16 * F + kk * 32);
    }

    f32x4 acco[2][8] = {};
    float m_r[2][4], l_r[2][4];
#pragma unroll
    for (int m = 0; m < 2; m++)
#pragma unroll
      for (int r = 0; r < 4; r++) { m_r[m][r] = -1e30f; l_r[m][r] = 0.f; }

    stage(0, 0);
    __syncthreads();

    for (int j = 0; j < nt; ++j) {
      const int cur = j & 1;
      if (j + 1 < nt) stage(j + 1, cur ^ 1);

      // ---- S = Q K^T ----
      const char* kbase = ((const char*)Kt) + cur * 16384;
      f32x4 accs[2][4] = {};
      __builtin_amdgcn_s_setprio(1);
#pragma unroll
      for (int ns = 0; ns < 4; ns++) {
        int n = ns * 16 + l15;
        const char* kb = kbase + n * 256;
#pragma unroll
        for (int kk = 0; kk < 4; kk++) {
          bf16x8 kf = *reinterpret_cast<const bf16x8*>(kb + (((kk * 4 + l4) ^ (n & 7)) << 4));
          accs[0][ns] = __builtin_amdgcn_mfma_f32_16x16x32_bf16(qf[0][kk], kf, accs[0][ns], 0, 0, 0);
          accs[1][ns] = __builtin_amdgcn_mfma_f32_16x16x32_bf16(qf[1][kk], kf, accs[1][ns], 0, 0, 0);
        }
      }
      __builtin_amdgcn_s_setprio(0);

      // ---- scale + causal mask ----
      const int qb = r0 + w * 32 + l4 * 4;   // + m*16 + r
      const int kvb = j * 64 + l15;          // + ns*16
      if (j >= 2 * t) {
#pragma unroll
        for (int m = 0; m < 2; m++)
#pragma unroll
          for (int ns = 0; ns < 4; ns++)
#pragma unroll
            for (int r = 0; r < 4; r++)
              accs[m][ns][r] = (kvb + ns * 16 > qb + m * 16 + r) ? -1e30f : accs[m][ns][r] * sc;
      } else {
#pragma unroll
        for (int m = 0; m < 2; m++)
#pragma unroll
          for (int ns = 0; ns < 4; ns++)
#pragma unroll
            for (int r = 0; r < 4; r++) accs[m][ns][r] *= sc;
      }

      // ---- online softmax (log2 domain), defer-max THR=8 ----
      float tm[2][4];
#pragma unroll
      for (int m = 0; m < 2; m++)
#pragma unroll
        for (int r = 0; r < 4; r++) {
          float a = fmaxf(fmaxf(accs[m][0][r], accs[m][1][r]), fmaxf(accs[m][2][r], accs[m][3][r]));
          a = fmaxf(a, __shfl_xor(a, 1));
          a = fmaxf(a, __shfl_xor(a, 2));
          a = fmaxf(a, __shfl_xor(a, 4));
          a = fmaxf(a, __shfl_xor(a, 8));
          tm[m][r] = a;
        }
      int needb = 0;
#pragma unroll
      for (int m = 0; m < 2; m++)
#pragma unroll
        for (int r = 0; r < 4; r++) needb |= (tm[m][r] > m_r[m][r] + 8.0f) ? 1 : 0;
      if (__any(needb)) {
#pragma unroll
        for (int m = 0; m < 2; m++)
#pragma unroll
          for (int r = 0; r < 4; r++) {
            float m2 = fmaxf(m_r[m][r], tm[m][r]);
            float fr = exp2f(m_r[m][r] - m2);
            m_r[m][r] = m2;
            l_r[m][r] *= fr;
#pragma unroll
            for (int ns = 0; ns < 8; ns++) acco[m][ns][r] *= fr;
          }
      }
      float ps[2][4] = {};
#pragma unroll
      for (int m = 0; m < 2; m++)
#pragma unroll
        for (int ns = 0; ns < 4; ns++)
#pragma unroll
          for (int r = 0; r < 4; r++) {
            float p = exp2f(accs[m][ns][r] - m_r[m][r]);
            ps[m][r] += p;
            int row = m * 16 + l4 * 4 + r;
            int kv2 = (ns * 16 + l15) * 2;
            *(u16*)(PlW + row * 128 + (kv2 ^ ((row & 7) << 4))) = f2bf(p);
          }
#pragma unroll
      for (int m = 0; m < 2; m++)
#pragma unroll
        for (int r = 0; r < 4; r++) {
          float s2 = ps[m][r];
          s2 += __shfl_xor(s2, 1);
          s2 += __shfl_xor(s2, 2);
          s2 += __shfl_xor(s2, 4);
          s2 += __shfl_xor(s2, 8);
          l_r[m][r] += s2;
        }

      // ---- O += P V ----
      const char* vbase = ((const char*)Vt) + cur * 16384;
      bf16x8 pf[2][2];
#pragma unroll
      for (int m = 0; m < 2; m++)
#pragma unroll
        for (int kk = 0; kk < 2; kk++) {
          int row = m * 16 + l15;
          pf[m][kk] = *reinterpret_cast<const bf16x8*>(PlW + row * 128 + (((kk * 4 + l4) ^ (row & 7)) << 4));
        }
      __builtin_amdgcn_s_setprio(1);
#pragma unroll
      for (int ns = 0; ns < 8; ns++) {
        int d = ns * 16 + l15;
        const char* vb = vbase + d * 128;
#pragma unroll
        for (int kk = 0; kk < 2; kk++) {
          bf16x8 vf = *reinterpret_cast<const bf16x8*>(vb + (((kk * 4 + l4) ^ (d & 7)) << 4));
          acco[0][ns] = __builtin_amdgcn_mfma_f32_16x16x32_bf16(pf[0][kk], vf, acco[0][ns], 0, 0, 0);
          acco[1][ns] = __builtin_amdgcn_mfma_f32_16x16x32_bf16(pf[1][kk], vf, acco[1][ns], 0, 0, 0);
        }
      }
      __builtin_amdgcn_s_setprio(0);

      __syncthreads();
    }

    // ---- epilogue: normalize + store ----
#pragma unroll
    for (int m = 0; m < 2; m++)
#pragma unroll
      for (int r = 0; r < 4; r++) {
        float inv = 1.f / l_r[m][r];
        size_t row = rowB + r0 + w * 32 + m * 16 + l4 * 4 + r;
#pragma unroll
        for (int ns = 0; ns < 8; ns++)
          out[row * E + h * 128 + ns * 16 + l15] = f2bf(acco[m][ns][r] * inv);
      }
  }
}

extern "C" void kernel_launch(void* const* d_in, const int* in_sizes, int n_in,
                              void* d_out, int out_size, void* d_ws, size_t ws_size,
                              hipStream_t stream) {
  const float* x = (const float*)d_in[0];
  const float* w_in = (const float*)d_in[1];
  const float* w_out = (const float*)d_in[2];
  float* out = (float*)d_out;
  char* ws = (char*)d_ws;

  // workspace layout (total ~169 MB)
  u16* xb = (u16*)(ws);                                   // 33,554,432 B (reused as attn out)
  u16* wib = (u16*)(ws + 33554432ull);                    // 50,331,648 B (reused as V^T images after gemm1)
  u16* wob = (u16*)(ws + 83886080ull);                    // 33,554,432 B
  u16* qkvb = (u16*)(ws + 117440512ull);                  // 50,331,648 B
  float* ct = (float*)(ws + 167772160ull);                // 524,288 B
  float* st = ct + 2048 * 64;                             // 524,288 B
  u16* attnb = xb;
  u16* vtg = wib;  // 8 MB, alias of wib (dead after gemm1)

  cvt_bf16<<<8192, 256, 0, stream>>>(x, xb, 16777216);
  cvt_bf16<<<12288, 256, 0, stream>>>(w_in, wib, 25165824);
  cvt_bf16<<<8192, 256, 0, stream>>>(w_out, wob, 16777216);
  rope_table<<<512, 256, 0, stream>>>(ct, st);
  gemm_bt<u16><<<dim3(48, 32), 256, 0, stream>>>(xb, wib, qkvb, 4096, 6144, 4096);
  rope_apply<<<5120, 256, 0, stream>>>(qkvb, ct, st);
  prep_vt<<<512, 256, 0, stream>>>(qkvb, vtg);
  attn_fwd<<<dim3(8, 64), 256, 0, stream>>>(qkvb, vtg, attnb);
  gemm_bt<float><<<dim3(32, 32), 256, 0, stream>>>(attnb, wob, out, 4096, 4096, 4096);
}

// Round 4
// 646.585 us; speedup vs baseline: 1.4033x; 1.1269x over previous
//
#include <hip/hip_runtime.h>
#include <hip/hip_bf16.h>
#include <stdint.h>

typedef unsigned short u16;
typedef __bf16 bf16x8 __attribute__((ext_vector_type(8)));
typedef u16 u16x8 __attribute__((ext_vector_type(8)));
typedef float f32x4 __attribute__((ext_vector_type(4)));

#define DEV __device__ __forceinline__
#define SBAR() asm volatile("s_barrier" ::: "memory")

DEV u16 f2bf(float f) {
  uint32_t u = __builtin_bit_cast(uint32_t, f);
  return (u16)((u + 0x7FFFu + ((u >> 16) & 1u)) >> 16);
}
DEV float bf2f(u16 h) { return __builtin_bit_cast(float, (uint32_t)h << 16); }

DEV void gload_lds16(const void* g, void* l) {
  __builtin_amdgcn_global_load_lds((const __attribute__((address_space(1))) uint32_t*)g,
                                   (__attribute__((address_space(3))) uint32_t*)l, 16, 0, 0);
}

// ---------------- elementwise f32 -> bf16 cast ----------------
__global__ void cvt_bf16(const float* __restrict__ in, u16* __restrict__ out, int n) {
  int i = (blockIdx.x * 256 + threadIdx.x) * 8;
  if (i >= n) return;
  const float4* p = reinterpret_cast<const float4*>(in + i);
  float4 a = p[0], b = p[1];
  u16x8 o;
  o[0] = f2bf(a.x); o[1] = f2bf(a.y); o[2] = f2bf(a.z); o[3] = f2bf(a.w);
  o[4] = f2bf(b.x); o[5] = f2bf(b.y); o[6] = f2bf(b.z); o[7] = f2bf(b.w);
  *reinterpret_cast<u16x8*>(out + i) = o;
}

// ---------------- RoPE cos/sin table (S=2048, 64 pairs) ----------------
__global__ void rope_table(float* __restrict__ ct, float* __restrict__ st) {
  int i = blockIdx.x * 256 + threadIdx.x;  // S*64 total
  int s = i >> 6, d = i & 63;
  float invf = powf(10000.0f, -(float)d * (1.0f / 64.0f));
  float ang = (float)s * invf;
  ct[i] = cosf(ang);
  st[i] = sinf(ang);
}

// ---------------- RoPE applied in-place on bf16 qkv ----------------
__global__ void rope_apply(u16* __restrict__ qkv, const float* __restrict__ ct, const float* __restrict__ st) {
  int idx = blockIdx.x * 256 + threadIdx.x;
  int grp = idx & 7;
  int head = (idx >> 3) % 40;
  int row = idx / 320;
  int s = row & 2047;
  size_t f0 = head < 32 ? (size_t)head * 128 : (size_t)4096 + (size_t)(head - 32) * 128;
  u16* p = qkv + (size_t)row * 6144 + f0 + grp * 8;
  u16x8 a = *reinterpret_cast<const u16x8*>(p);
  u16x8 b = *reinterpret_cast<const u16x8*>(p + 64);
  const float4* cp = reinterpret_cast<const float4*>(ct + s * 64 + grp * 8);
  const float4* sp = reinterpret_cast<const float4*>(st + s * 64 + grp * 8);
  float4 c0 = cp[0], c1 = cp[1], s0 = sp[0], s1 = sp[1];
  float cc[8] = {c0.x, c0.y, c0.z, c0.w, c1.x, c1.y, c1.z, c1.w};
  float ss[8] = {s0.x, s0.y, s0.z, s0.w, s1.x, s1.y, s1.z, s1.w};
  u16x8 o1, o2;
#pragma unroll
  for (int i = 0; i < 8; i++) {
    float x1 = bf2f(a[i]), x2 = bf2f(b[i]);
    o1[i] = f2bf(x1 * cc[i] - x2 * ss[i]);
    o2[i] = f2bf(x2 * cc[i] + x1 * ss[i]);
  }
  *reinterpret_cast<u16x8*>(p) = o1;
  *reinterpret_cast<u16x8*>(p + 64) = o2;
}

// ---------------- V^T tile image prep ----------------
__global__ void prep_vt(const u16* __restrict__ qkv, u16* __restrict__ vtg) {
  int id = blockIdx.x;  // (b*8+kvh)*32 + j
  int j = id & 31, kvh = (id >> 5) & 7, b = id >> 8;
  const int tid = threadIdx.x;
  const size_t rowB = (size_t)b * 2048;
  u16* img = vtg + (size_t)id * 8192;
#pragma unroll
  for (int p = 0; p < 4; p++) {
    int lin = p * 256 + tid;
    int d = lin >> 3, c = lin & 7;
    const u16* src = qkv + (rowB + j * 64 + c * 8) * 6144 + 5120 + kvh * 128 + d;
    u16x8 v;
#pragma unroll
    for (int i = 0; i < 8; i++) v[i] = src[(size_t)i * 6144];
    *reinterpret_cast<u16x8*>(img + d * 64 + ((c ^ (d & 7)) << 3)) = v;
  }
}

// ---------------- 256x256 8-phase GEMM: C[M][N] = A[M][K] * B[N][K]^T ----------------
DEV void store_c(float* C, size_t idx, float v) { C[idx] = v; }
DEV void store_c(u16* C, size_t idx, float v) { C[idx] = f2bf(v); }

// LDS layout (bytes): A buf0 [0,32K) buf1 [32K,64K); B buf0 [64K,96K) buf1 [96K,128K).
// Tile image: 256 rows x 64 cols bf16, row stride 128B, st-swizzle: byte ^= ((byte>>9)&1)<<5.
// Hazard table (region -> last ds_read phase): A0:P3, A1:P3, B0:P2, B1:P2.
// Stage placement: P1: A1(t+1) [other buf]; P3: B0(t+2); P4: A0(t+2), B1(t+2).
template <typename OutT>
__global__ __launch_bounds__(512, 2) void gemm256(const u16* __restrict__ A, const u16* __restrict__ B,
                                                  OutT* __restrict__ C, int M, int N, int K) {
  __shared__ __align__(16) u16 lds[65536];  // 128 KiB
  char* LB = (char*)lds;
  const int tid = threadIdx.x;
  const int w = tid >> 6, lane = tid & 63;
  const int l15 = lane & 15, l4 = lane >> 4;
  const int wm = w >> 2, wn = w & 3;

  // bijective XCD swizzle on 1-D grid
  int nwg = gridDim.x;
  int q = nwg >> 3, rr = nwg & 7;
  int xcd = blockIdx.x & 7, idx = blockIdx.x >> 3;
  int sw = (xcd < rr ? xcd * (q + 1) : rr * (q + 1) + (xcd - rr) * q) + idx;
  int gxn = N >> 8;
  int by = sw / gxn, bx = sw - by * gxn;
  const int row0 = by << 8, col0 = bx << 8;
  const int NT = K >> 6;

  // staging: round covers 64 rows; lane -> row w*8+(lane>>3), 16B chunk lane&7
  const int srow = w * 8 + (lane >> 3);
  const int sc16 = (lane & 7) ^ (((lane >> 5) & 1) << 1);  // inverse-swizzled source chunk
  const u16* gA = A + (size_t)(row0 + srow) * K + sc16 * 8;
  const u16* gB = B + (size_t)(col0 + srow) * K + sc16 * 8;

  // ds_read swizzle: flip byte-bit5 when row bit2 (== l15 bit2) set
  const int fl = ((l15 >> 2) & 1) << 5;
  const int aoff = (wm * 128 + l15) * 128 + l4 * 16;
  const int boff = (wn * 64 + l15) * 128 + l4 * 16;

  f32x4 acc[8][4] = {};
  bf16x8 fA[4][2], fB0[2][2], fBc[2][2];

#define STAGE_A(kt, h, base)                                                      \
  {                                                                               \
    const u16* g_ = gA + (size_t)((h)*128) * K + (size_t)(kt)*64;                 \
    gload_lds16(g_, (base) + (h)*16384 + w * 1024);                               \
    gload_lds16(g_ + (size_t)64 * K, (base) + (h)*16384 + 8192 + w * 1024);       \
  }
#define STAGE_B(kt, h, base)                                                      \
  {                                                                               \
    const u16* g_ = gB + (size_t)((h)*128) * K + (size_t)(kt)*64;                 \
    gload_lds16(g_, (base) + (h)*16384 + w * 1024);                               \
    gload_lds16(g_ + (size_t)64 * K, (base) + (h)*16384 + 8192 + w * 1024);       \
  }
#define MFMA_Q(FB, MH, NH)                                                        \
  _Pragma("unroll") for (int kk = 0; kk < 2; kk++) {                              \
    _Pragma("unroll") for (int mf = 0; mf < 4; mf++) {                            \
      _Pragma("unroll") for (int nf = 0; nf < 2; nf++) {                          \
        acc[(MH)*4 + mf][(NH)*2 + nf] = __builtin_amdgcn_mfma_f32_16x16x32_bf16(  \
            fA[mf][kk], FB[nf][kk], acc[(MH)*4 + mf][(NH)*2 + nf], 0, 0, 0);      \
      }                                                                           \
    }                                                                             \
  }

  // prologue: tile0 {A0,A1,B0,B1} -> buf0; tile1 {A0,B0,B1} -> buf1 (A1(1) staged at t=0 P1)
  STAGE_A(0, 0, LB);
  STAGE_A(0, 1, LB);
  STAGE_B(0, 0, LB + 65536);
  STAGE_B(0, 1, LB + 65536);
  STAGE_A(1, 0, LB + 32768);
  STAGE_B(1, 0, LB + 98304);
  STAGE_B(1, 1, LB + 98304);
  asm volatile("s_waitcnt vmcnt(6)" ::: "memory");
  SBAR();

  for (int t = 0; t < NT; ++t) {
    char* ac = LB + (t & 1) * 32768;
    char* bc = LB + 65536 + (t & 1) * 32768;
    char* an = LB + ((t + 1) & 1) * 32768;

    // ---- P1: read A rows [wm*128, +64) (8) + B rows [wn*64, +32) (4); stage (t+1).A1 -> other buf ----
#pragma unroll
    for (int mf = 0; mf < 4; mf++)
#pragma unroll
      for (int kk = 0; kk < 2; kk++)
        fA[mf][kk] = *(const bf16x8*)(ac + ((aoff + mf * 2048 + kk * 64) ^ fl));
#pragma unroll
    for (int nf = 0; nf < 2; nf++)
#pragma unroll
      for (int kk = 0; kk < 2; kk++)
        fB0[nf][kk] = *(const bf16x8*)(bc + ((boff + nf * 2048 + kk * 64) ^ fl));
    if (t + 1 < NT) STAGE_A(t + 1, 1, an);
    asm volatile("s_waitcnt lgkmcnt(8)" ::: "memory");
    SBAR();
    asm volatile("s_waitcnt lgkmcnt(0)" ::: "memory");
    __builtin_amdgcn_sched_barrier(0);
    __builtin_amdgcn_s_setprio(1);
    MFMA_Q(fB0, 0, 0);
    __builtin_amdgcn_s_setprio(0);
    SBAR();

    // ---- P2: read B rows [wn*64+32, +32) (4); NO stage (A0 still read at P3) ----
#pragma unroll
    for (int nf = 0; nf < 2; nf++)
#pragma unroll
      for (int kk = 0; kk < 2; kk++)
        fBc[nf][kk] = *(const bf16x8*)(bc + ((boff + (nf + 2) * 2048 + kk * 64) ^ fl));
    SBAR();
    asm volatile("s_waitcnt lgkmcnt(0)" ::: "memory");
    __builtin_amdgcn_sched_barrier(0);
    __builtin_amdgcn_s_setprio(1);
    MFMA_Q(fBc, 0, 1);
    __builtin_amdgcn_s_setprio(0);
    SBAR();

    // ---- P3: read A rows [wm*128+64, +64) (8); stage (t+2).B0 (B0 last read P2) ----
#pragma unroll
    for (int mf = 0; mf < 4; mf++)
#pragma unroll
      for (int kk = 0; kk < 2; kk++)
        fA[mf][kk] = *(const bf16x8*)(ac + ((aoff + (mf + 4) * 2048 + kk * 64) ^ fl));
    if (t + 2 < NT) STAGE_B(t + 2, 0, bc);
    SBAR();
    asm volatile("s_waitcnt lgkmcnt(0)" ::: "memory");
    __builtin_amdgcn_sched_barrier(0);
    __builtin_amdgcn_s_setprio(1);
    MFMA_Q(fBc, 1, 1);
    __builtin_amdgcn_s_setprio(0);
    SBAR();

    // ---- P4: no reads; stage (t+2).A0 (A0 last read P3) + (t+2).B1 (last read P2) ----
    if (t + 2 < NT) {
      STAGE_A(t + 2, 0, ac);
      STAGE_B(t + 2, 1, bc);
    }
    SBAR();
    __builtin_amdgcn_s_setprio(1);
    MFMA_Q(fB0, 1, 0);
    __builtin_amdgcn_s_setprio(0);
    // K-tile boundary: counted vmcnt — keeps newest 6 = {B0,A0,B1 of t+2}, forces all of t+1
    if (t <= NT - 3) {
      asm volatile("s_waitcnt vmcnt(6)" ::: "memory");
      SBAR();
    } else if (t < NT - 1) {
      asm volatile("s_waitcnt vmcnt(0)" ::: "memory");
      SBAR();
    }
  }

  // epilogue: C write
#pragma unroll
  for (int mf = 0; mf < 8; mf++)
#pragma unroll
    for (int nf = 0; nf < 4; nf++)
#pragma unroll
      for (int r = 0; r < 4; r++) {
        size_t row = (size_t)row0 + wm * 128 + mf * 16 + l4 * 4 + r;
        size_t col = (size_t)col0 + wn * 64 + nf * 16 + l15;
        store_c(C, row * (size_t)N + col, acc[mf][nf][r]);
      }
#undef STAGE_A
#undef STAGE_B
#undef MFMA_Q
}

// ---------------- causal GQA flash attention (unchanged, round-2 proven) ----------------
__global__ __launch_bounds__(256, 2) void attn_fwd(const u16* __restrict__ qkv,
                                                   const u16* __restrict__ vtg,
                                                   u16* __restrict__ out) {
  constexpr int S = 2048, F = 6144, E = 4096;
  __shared__ __align__(16) u16 Kt[2 * 8192];
  __shared__ __align__(16) u16 Vt[2 * 8192];
  __shared__ __align__(16) u16 Pl[4 * 2048];

  const int tid = threadIdx.x;
  const int w = tid >> 6, lane = tid & 63;
  const int l15 = lane & 15, l4 = lane >> 4;
  const int pair = blockIdx.x;  // 0..7
  const int b = blockIdx.y >> 5, h = blockIdx.y & 31, kvh = h >> 2;
  const size_t rowB = (size_t)b * S;
  const float sc = 0.08838834764831845f * 1.4426950408889634f;
  const int sgn = tid >> 4, sgc = tid & 15;
  char* PlW = ((char*)Pl) + w * 4096;
  const size_t vtb = (size_t)(b * 8 + kvh) * 32 * 8192;

  auto stage = [&](int j, int buf) {
    char* kd = ((char*)Kt) + buf * 16384 + w * 1024;
    char* vd = ((char*)Vt) + buf * 16384 + w * 1024;
    const u16* vs = vtg + vtb + (size_t)j * 8192 + tid * 8;
#pragma unroll
    for (int p = 0; p < 4; p++) {
      int n = p * 16 + sgn;
      const u16* g = qkv + (rowB + j * 64 + n) * F + 4096 + kvh * 128 + (sgc ^ (n & 7)) * 8;
      gload_lds16(g, kd + p * 4096);
      gload_lds16(vs + p * 2048, vd + p * 4096);
    }
  };

  for (int half = 0; half < 2; ++half) {
    const int t = half ? 15 - pair : pair;
    const int nt = 2 * t + 2;
    const int r0 = t * 128;

    bf16x8 qf[2][4];
    {
      const u16* qp = qkv + (rowB + r0 + w * 32 + l15) * F + h * 128 + l4 * 8;
#pragma unroll
      for (int m = 0; m < 2; m++)
#pragma unroll
        for (int kk = 0; kk < 4; kk++)
          qf[m][kk] = *reinterpret_cast<const bf16x8*>(qp + (size_t)m * 16 * F + kk * 32);
    }

    f32x4 acco[2][8] = {};
    float m_r[2][4], l_r[2][4];
#pragma unroll
    for (int m = 0; m < 2; m++)
#pragma unroll
      for (int r = 0; r < 4; r++) { m_r[m][r] = -1e30f; l_r[m][r] = 0.f; }

    stage(0, 0);
    __syncthreads();

    for (int j = 0; j < nt; ++j) {
      const int cur = j & 1;
      if (j + 1 < nt) stage(j + 1, cur ^ 1);

      const char* kbase = ((const char*)Kt) + cur * 16384;
      f32x4 accs[2][4] = {};
      __builtin_amdgcn_s_setprio(1);
#pragma unroll
      for (int ns = 0; ns < 4; ns++) {
        int n = ns * 16 + l15;
        const char* kb = kbase + n * 256;
#pragma unroll
        for (int kk = 0; kk < 4; kk++) {
          bf16x8 kf = *reinterpret_cast<const bf16x8*>(kb + (((kk * 4 + l4) ^ (n & 7)) << 4));
          accs[0][ns] = __builtin_amdgcn_mfma_f32_16x16x32_bf16(qf[0][kk], kf, accs[0][ns], 0, 0, 0);
          accs[1][ns] = __builtin_amdgcn_mfma_f32_16x16x32_bf16(qf[1][kk], kf, accs[1][ns], 0, 0, 0);
        }
      }
      __builtin_amdgcn_s_setprio(0);

      const int qb = r0 + w * 32 + l4 * 4;
      const int kvb = j * 64 + l15;
      if (j >= 2 * t) {
#pragma unroll
        for (int m = 0; m < 2; m++)
#pragma unroll
          for (int ns = 0; ns < 4; ns++)
#pragma unroll
            for (int r = 0; r < 4; r++)
              accs[m][ns][r] = (kvb + ns * 16 > qb + m * 16 + r) ? -1e30f : accs[m][ns][r] * sc;
      } else {
#pragma unroll
        for (int m = 0; m < 2; m++)
#pragma unroll
          for (int ns = 0; ns < 4; ns++)
#pragma unroll
            for (int r = 0; r < 4; r++) accs[m][ns][r] *= sc;
      }

      float tm[2][4];
#pragma unroll
      for (int m = 0; m < 2; m++)
#pragma unroll
        for (int r = 0; r < 4; r++) {
          float a = fmaxf(fmaxf(accs[m][0][r], accs[m][1][r]), fmaxf(accs[m][2][r], accs[m][3][r]));
          a = fmaxf(a, __shfl_xor(a, 1));
          a = fmaxf(a, __shfl_xor(a, 2));
          a = fmaxf(a, __shfl_xor(a, 4));
          a = fmaxf(a, __shfl_xor(a, 8));
          tm[m][r] = a;
        }
      int needb = 0;
#pragma unroll
      for (int m = 0; m < 2; m++)
#pragma unroll
        for (int r = 0; r < 4; r++) needb |= (tm[m][r] > m_r[m][r] + 8.0f) ? 1 : 0;
      if (__any(needb)) {
#pragma unroll
        for (int m = 0; m < 2; m++)
#pragma unroll
          for (int r = 0; r < 4; r++) {
            float m2 = fmaxf(m_r[m][r], tm[m][r]);
            float fr = exp2f(m_r[m][r] - m2);
            m_r[m][r] = m2;
            l_r[m][r] *= fr;
#pragma unroll
            for (int ns = 0; ns < 8; ns++) acco[m][ns][r] *= fr;
          }
      }
      float ps[2][4] = {};
#pragma unroll
      for (int m = 0; m < 2; m++)
#pragma unroll
        for (int ns = 0; ns < 4; ns++)
#pragma unroll
          for (int r = 0; r < 4; r++) {
            float p = exp2f(accs[m][ns][r] - m_r[m][r]);
            ps[m][r] += p;
            int row = m * 16 + l4 * 4 + r;
            int kv2 = (ns * 16 + l15) * 2;
            *(u16*)(PlW + row * 128 + (kv2 ^ ((row & 7) << 4))) = f2bf(p);
          }
#pragma unroll
      for (int m = 0; m < 2; m++)
#pragma unroll
        for (int r = 0; r < 4; r++) {
          float s2 = ps[m][r];
          s2 += __shfl_xor(s2, 1);
          s2 += __shfl_xor(s2, 2);
          s2 += __shfl_xor(s2, 4);
          s2 += __shfl_xor(s2, 8);
          l_r[m][r] += s2;
        }

      const char* vbase = ((const char*)Vt) + cur * 16384;
      bf16x8 pf[2][2];
#pragma unroll
      for (int m = 0; m < 2; m++)
#pragma unroll
        for (int kk = 0; kk < 2; kk++) {
          int row = m * 16 + l15;
          pf[m][kk] = *reinterpret_cast<const bf16x8*>(PlW + row * 128 + (((kk * 4 + l4) ^ (row & 7)) << 4));
        }
      __builtin_amdgcn_s_setprio(1);
#pragma unroll
      for (int ns = 0; ns < 8; ns++) {
        int d = ns * 16 + l15;
        const char* vb = vbase + d * 128;
#pragma unroll
        for (int kk = 0; kk < 2; kk++) {
          bf16x8 vf = *reinterpret_cast<const bf16x8*>(vb + (((kk * 4 + l4) ^ (d & 7)) << 4));
          acco[0][ns] = __builtin_amdgcn_mfma_f32_16x16x32_bf16(pf[0][kk], vf, acco[0][ns], 0, 0, 0);
          acco[1][ns] = __builtin_amdgcn_mfma_f32_16x16x32_bf16(pf[1][kk], vf, acco[1][ns], 0, 0, 0);
        }
      }
      __builtin_amdgcn_s_setprio(0);

      __syncthreads();
    }

#pragma unroll
    for (int m = 0; m < 2; m++)
#pragma unroll
      for (int r = 0; r < 4; r++) {
        float inv = 1.f / l_r[m][r];
        size_t row = rowB + r0 + w * 32 + m * 16 + l4 * 4 + r;
#pragma unroll
        for (int ns = 0; ns < 8; ns++)
          out[row * E + h * 128 + ns * 16 + l15] = f2bf(acco[m][ns][r] * inv);
      }
  }
}

extern "C" void kernel_launch(void* const* d_in, const int* in_sizes, int n_in,
                              void* d_out, int out_size, void* d_ws, size_t ws_size,
                              hipStream_t stream) {
  const float* x = (const float*)d_in[0];
  const float* w_in = (const float*)d_in[1];
  const float* w_out = (const float*)d_in[2];
  float* out = (float*)d_out;
  char* ws = (char*)d_ws;

  u16* xb = (u16*)(ws);                                   // 33,554,432 B (reused as attn out)
  u16* wib = (u16*)(ws + 33554432ull);                    // 50,331,648 B (reused as V^T images)
  u16* wob = (u16*)(ws + 83886080ull);                    // 33,554,432 B
  u16* qkvb = (u16*)(ws + 117440512ull);                  // 50,331,648 B
  float* ct = (float*)(ws + 167772160ull);                // 524,288 B
  float* st = ct + 2048 * 64;                             // 524,288 B
  u16* attnb = xb;
  u16* vtg = wib;

  cvt_bf16<<<8192, 256, 0, stream>>>(x, xb, 16777216);
  cvt_bf16<<<12288, 256, 0, stream>>>(w_in, wib, 25165824);
  cvt_bf16<<<8192, 256, 0, stream>>>(w_out, wob, 16777216);
  rope_table<<<512, 256, 0, stream>>>(ct, st);
  gemm256<u16><<<384, 512, 0, stream>>>(xb, wib, qkvb, 4096, 6144, 4096);
  rope_apply<<<5120, 256, 0, stream>>>(qkvb, ct, st);
  prep_vt<<<512, 256, 0, stream>>>(qkvb, vtg);
  attn_fwd<<<dim3(8, 64), 256, 0, stream>>>(qkvb, vtg, attnb);
  gemm256<float><<<256, 512, 0, stream>>>(attnb, wob, out, 4096, 4096, 4096);
}

// Round 5
// 601.722 us; speedup vs baseline: 1.5079x; 1.0746x over previous
//
#include <hip/hip_runtime.h>
#include <hip/hip_bf16.h>
#include <stdint.h>

typedef unsigned short u16;
typedef __bf16 bf16x8 __attribute__((ext_vector_type(8)));
typedef u16 u16x8 __attribute__((ext_vector_type(8)));
typedef float f32x4 __attribute__((ext_vector_type(4)));

#define DEV __device__ __forceinline__
#define SBAR() asm volatile("s_barrier" ::: "memory")

DEV u16 f2bf(float f) {
  uint32_t u = __builtin_bit_cast(uint32_t, f);
  return (u16)((u + 0x7FFFu + ((u >> 16) & 1u)) >> 16);
}
DEV float bf2f(u16 h) { return __builtin_bit_cast(float, (uint32_t)h << 16); }

DEV void gload_lds16(const void* g, void* l) {
  __builtin_amdgcn_global_load_lds((const __attribute__((address_space(1))) uint32_t*)g,
                                   (__attribute__((address_space(3))) uint32_t*)l, 16, 0, 0);
}

// ---------------- elementwise f32 -> bf16 cast ----------------
__global__ void cvt_bf16(const float* __restrict__ in, u16* __restrict__ out, int n) {
  int i = (blockIdx.x * 256 + threadIdx.x) * 8;
  if (i >= n) return;
  const float4* p = reinterpret_cast<const float4*>(in + i);
  float4 a = p[0], b = p[1];
  u16x8 o;
  o[0] = f2bf(a.x); o[1] = f2bf(a.y); o[2] = f2bf(a.z); o[3] = f2bf(a.w);
  o[4] = f2bf(b.x); o[5] = f2bf(b.y); o[6] = f2bf(b.z); o[7] = f2bf(b.w);
  *reinterpret_cast<u16x8*>(out + i) = o;
}

// ---------------- RoPE cos/sin table (S=2048, 64 pairs) ----------------
__global__ void rope_table(float* __restrict__ ct, float* __restrict__ st) {
  int i = blockIdx.x * 256 + threadIdx.x;  // S*64 total
  int s = i >> 6, d = i & 63;
  float invf = powf(10000.0f, -(float)d * (1.0f / 64.0f));
  float ang = (float)s * invf;
  ct[i] = cosf(ang);
  st[i] = sinf(ang);
}

// ---------------- RoPE applied in-place on bf16 qkv ----------------
__global__ void rope_apply(u16* __restrict__ qkv, const float* __restrict__ ct, const float* __restrict__ st) {
  int idx = blockIdx.x * 256 + threadIdx.x;
  int grp = idx & 7;
  int head = (idx >> 3) % 40;
  int row = idx / 320;
  int s = row & 2047;
  size_t f0 = head < 32 ? (size_t)head * 128 : (size_t)4096 + (size_t)(head - 32) * 128;
  u16* p = qkv + (size_t)row * 6144 + f0 + grp * 8;
  u16x8 a = *reinterpret_cast<const u16x8*>(p);
  u16x8 b = *reinterpret_cast<const u16x8*>(p + 64);
  const float4* cp = reinterpret_cast<const float4*>(ct + s * 64 + grp * 8);
  const float4* sp = reinterpret_cast<const float4*>(st + s * 64 + grp * 8);
  float4 c0 = cp[0], c1 = cp[1], s0 = sp[0], s1 = sp[1];
  float cc[8] = {c0.x, c0.y, c0.z, c0.w, c1.x, c1.y, c1.z, c1.w};
  float ss[8] = {s0.x, s0.y, s0.z, s0.w, s1.x, s1.y, s1.z, s1.w};
  u16x8 o1, o2;
#pragma unroll
  for (int i = 0; i < 8; i++) {
    float x1 = bf2f(a[i]), x2 = bf2f(b[i]);
    o1[i] = f2bf(x1 * cc[i] - x2 * ss[i]);
    o2[i] = f2bf(x2 * cc[i] + x1 * ss[i]);
  }
  *reinterpret_cast<u16x8*>(p) = o1;
  *reinterpret_cast<u16x8*>(p + 64) = o2;
}

// ---------------- V^T tile image prep ----------------
__global__ void prep_vt(const u16* __restrict__ qkv, u16* __restrict__ vtg) {
  int id = blockIdx.x;  // (b*8+kvh)*32 + j
  int j = id & 31, kvh = (id >> 5) & 7, b = id >> 8;
  const int tid = threadIdx.x;
  const size_t rowB = (size_t)b * 2048;
  u16* img = vtg + (size_t)id * 8192;
#pragma unroll
  for (int p = 0; p < 4; p++) {
    int lin = p * 256 + tid;
    int d = lin >> 3, c = lin & 7;
    const u16* src = qkv + (rowB + j * 64 + c * 8) * 6144 + 5120 + kvh * 128 + d;
    u16x8 v;
#pragma unroll
    for (int i = 0; i < 8; i++) v[i] = src[(size_t)i * 6144];
    *reinterpret_cast<u16x8*>(img + d * 64 + ((c ^ (d & 7)) << 3)) = v;
  }
}

// ---------------- 256x256 8-phase GEMM: C[M][N] = A[M][K] * B[N][K]^T ----------------
DEV void store_c(float* C, size_t idx, float v) { C[idx] = v; }
DEV void store_c(u16* C, size_t idx, float v) { C[idx] = f2bf(v); }

// LDS layout (bytes): A buf0 [0,32K) buf1 [32K,64K); B buf0 [64K,96K) buf1 [96K,128K).
// Tile image: 256 rows x 64 cols bf16, row stride 128B.
// Full 3-bit slot swizzle: 16B-slot' = slot ^ (row&7)  (read: byte ^= (l15&7)<<4;
// stage source chunk: (lane&7) ^ ((lane>>3)&7) since linear LDS dest row&7 = (lane>>3)&7).
// Hazard table (region -> last ds_read phase): A0:P3, A1:P3, B0:P2, B1:P2.
// Stage placement: P1: A1(t+1) [other buf]; P3: B0(t+2); P4: A0(t+2), B1(t+2).
template <typename OutT>
__global__ __launch_bounds__(512, 2) void gemm256(const u16* __restrict__ A, const u16* __restrict__ B,
                                                  OutT* __restrict__ C, int M, int N, int K) {
  __shared__ __align__(16) u16 lds[65536];  // 128 KiB
  char* LB = (char*)lds;
  const int tid = threadIdx.x;
  const int w = tid >> 6, lane = tid & 63;
  const int l15 = lane & 15, l4 = lane >> 4;
  const int wm = w >> 2, wn = w & 3;

  // bijective XCD swizzle on 1-D grid
  int nwg = gridDim.x;
  int q = nwg >> 3, rr = nwg & 7;
  int xcd = blockIdx.x & 7, idx = blockIdx.x >> 3;
  int sw = (xcd < rr ? xcd * (q + 1) : rr * (q + 1) + (xcd - rr) * q) + idx;
  int gxn = N >> 8;
  int by = sw / gxn, bx = sw - by * gxn;
  const int row0 = by << 8, col0 = bx << 8;
  const int NT = K >> 6;

  // staging: round covers 64 rows; lane -> row w*8+(lane>>3), 16B chunk lane&7
  const int srow = w * 8 + (lane >> 3);
  const int sc16 = (lane & 7) ^ ((lane >> 3) & 7);  // inverse-swizzled source chunk
  const u16* gA = A + (size_t)(row0 + srow) * K + sc16 * 8;
  const u16* gB = B + (size_t)(col0 + srow) * K + sc16 * 8;

  // ds_read swizzle: slot ^= row&7 (row&7 == l15&7 for all fragment reads)
  const int fl = (l15 & 7) << 4;
  const int aoff = (wm * 128 + l15) * 128 + l4 * 16;
  const int boff = (wn * 64 + l15) * 128 + l4 * 16;

  f32x4 acc[8][4] = {};
  bf16x8 fA[4][2], fB0[2][2], fBc[2][2];

#define STAGE_A(kt, h, base)                                                      \
  {                                                                               \
    const u16* g_ = gA + (size_t)((h)*128) * K + (size_t)(kt)*64;                 \
    gload_lds16(g_, (base) + (h)*16384 + w * 1024);                               \
    gload_lds16(g_ + (size_t)64 * K, (base) + (h)*16384 + 8192 + w * 1024);       \
  }
#define STAGE_B(kt, h, base)                                                      \
  {                                                                               \
    const u16* g_ = gB + (size_t)((h)*128) * K + (size_t)(kt)*64;                 \
    gload_lds16(g_, (base) + (h)*16384 + w * 1024);                               \
    gload_lds16(g_ + (size_t)64 * K, (base) + (h)*16384 + 8192 + w * 1024);       \
  }
#define MFMA_Q(FB, MH, NH)                                                        \
  _Pragma("unroll") for (int kk = 0; kk < 2; kk++) {                              \
    _Pragma("unroll") for (int mf = 0; mf < 4; mf++) {                            \
      _Pragma("unroll") for (int nf = 0; nf < 2; nf++) {                          \
        acc[(MH)*4 + mf][(NH)*2 + nf] = __builtin_amdgcn_mfma_f32_16x16x32_bf16(  \
            fA[mf][kk], FB[nf][kk], acc[(MH)*4 + mf][(NH)*2 + nf], 0, 0, 0);      \
      }                                                                           \
    }                                                                             \
  }

  // prologue: tile0 {A0,A1,B0,B1} -> buf0; tile1 {A0,B0,B1} -> buf1 (A1(1) staged at t=0 P1)
  STAGE_A(0, 0, LB);
  STAGE_A(0, 1, LB);
  STAGE_B(0, 0, LB + 65536);
  STAGE_B(0, 1, LB + 65536);
  STAGE_A(1, 0, LB + 32768);
  STAGE_B(1, 0, LB + 98304);
  STAGE_B(1, 1, LB + 98304);
  asm volatile("s_waitcnt vmcnt(6)" ::: "memory");
  SBAR();

  for (int t = 0; t < NT; ++t) {
    char* ac = LB + (t & 1) * 32768;
    char* bc = LB + 65536 + (t & 1) * 32768;
    char* an = LB + ((t + 1) & 1) * 32768;

    // ---- P1: read A rows [wm*128, +64) (8) + B rows [wn*64, +32) (4); stage (t+1).A1 -> other buf ----
#pragma unroll
    for (int mf = 0; mf < 4; mf++)
#pragma unroll
      for (int kk = 0; kk < 2; kk++)
        fA[mf][kk] = *(const bf16x8*)(ac + ((aoff + mf * 2048 + kk * 64) ^ fl));
#pragma unroll
    for (int nf = 0; nf < 2; nf++)
#pragma unroll
      for (int kk = 0; kk < 2; kk++)
        fB0[nf][kk] = *(const bf16x8*)(bc + ((boff + nf * 2048 + kk * 64) ^ fl));
    if (t + 1 < NT) STAGE_A(t + 1, 1, an);
    asm volatile("s_waitcnt lgkmcnt(8)" ::: "memory");
    SBAR();
    asm volatile("s_waitcnt lgkmcnt(0)" ::: "memory");
    __builtin_amdgcn_sched_barrier(0);
    __builtin_amdgcn_s_setprio(1);
    MFMA_Q(fB0, 0, 0);
    __builtin_amdgcn_s_setprio(0);
    SBAR();

    // ---- P2: read B rows [wn*64+32, +32) (4); NO stage (A0 still read at P3) ----
#pragma unroll
    for (int nf = 0; nf < 2; nf++)
#pragma unroll
      for (int kk = 0; kk < 2; kk++)
        fBc[nf][kk] = *(const bf16x8*)(bc + ((boff + (nf + 2) * 2048 + kk * 64) ^ fl));
    SBAR();
    asm volatile("s_waitcnt lgkmcnt(0)" ::: "memory");
    __builtin_amdgcn_sched_barrier(0);
    __builtin_amdgcn_s_setprio(1);
    MFMA_Q(fBc, 0, 1);
    __builtin_amdgcn_s_setprio(0);
    SBAR();

    // ---- P3: read A rows [wm*128+64, +64) (8); stage (t+2).B0 (B0 last read P2) ----
#pragma unroll
    for (int mf = 0; mf < 4; mf++)
#pragma unroll
      for (int kk = 0; kk < 2; kk++)
        fA[mf][kk] = *(const bf16x8*)(ac + ((aoff + (mf + 4) * 2048 + kk * 64) ^ fl));
    if (t + 2 < NT) STAGE_B(t + 2, 0, bc);
    SBAR();
    asm volatile("s_waitcnt lgkmcnt(0)" ::: "memory");
    __builtin_amdgcn_sched_barrier(0);
    __builtin_amdgcn_s_setprio(1);
    MFMA_Q(fBc, 1, 1);
    __builtin_amdgcn_s_setprio(0);
    SBAR();

    // ---- P4: no reads; stage (t+2).A0 (A0 last read P3) + (t+2).B1 (last read P2) ----
    if (t + 2 < NT) {
      STAGE_A(t + 2, 0, ac);
      STAGE_B(t + 2, 1, bc);
    }
    SBAR();
    __builtin_amdgcn_s_setprio(1);
    MFMA_Q(fB0, 1, 0);
    __builtin_amdgcn_s_setprio(0);
    // K-tile boundary: counted vmcnt — keeps newest 6 = {B0,A0,B1 of t+2}, forces all of t+1
    if (t <= NT - 3) {
      asm volatile("s_waitcnt vmcnt(6)" ::: "memory");
      SBAR();
    } else if (t < NT - 1) {
      asm volatile("s_waitcnt vmcnt(0)" ::: "memory");
      SBAR();
    }
  }

  // epilogue: C write
#pragma unroll
  for (int mf = 0; mf < 8; mf++)
#pragma unroll
    for (int nf = 0; nf < 4; nf++)
#pragma unroll
      for (int r = 0; r < 4; r++) {
        size_t row = (size_t)row0 + wm * 128 + mf * 16 + l4 * 4 + r;
        size_t col = (size_t)col0 + wn * 64 + nf * 16 + l15;
        store_c(C, row * (size_t)N + col, acc[mf][nf][r]);
      }
#undef STAGE_A
#undef STAGE_B
#undef MFMA_Q
}

// ---------------- causal GQA flash attention (unchanged, round-2 proven) ----------------
__global__ __launch_bounds__(256, 2) void attn_fwd(const u16* __restrict__ qkv,
                                                   const u16* __restrict__ vtg,
                                                   u16* __restrict__ out) {
  constexpr int S = 2048, F = 6144, E = 4096;
  __shared__ __align__(16) u16 Kt[2 * 8192];
  __shared__ __align__(16) u16 Vt[2 * 8192];
  __shared__ __align__(16) u16 Pl[4 * 2048];

  const int tid = threadIdx.x;
  const int w = tid >> 6, lane = tid & 63;
  const int l15 = lane & 15, l4 = lane >> 4;
  const int pair = blockIdx.x;  // 0..7
  const int b = blockIdx.y >> 5, h = blockIdx.y & 31, kvh = h >> 2;
  const size_t rowB = (size_t)b * S;
  const float sc = 0.08838834764831845f * 1.4426950408889634f;
  const int sgn = tid >> 4, sgc = tid & 15;
  char* PlW = ((char*)Pl) + w * 4096;
  const size_t vtb = (size_t)(b * 8 + kvh) * 32 * 8192;

  auto stage = [&](int j, int buf) {
    char* kd = ((char*)Kt) + buf * 16384 + w * 1024;
    char* vd = ((char*)Vt) + buf * 16384 + w * 1024;
    const u16* vs = vtg + vtb + (size_t)j * 8192 + tid * 8;
#pragma unroll
    for (int p = 0; p < 4; p++) {
      int n = p * 16 + sgn;
      const u16* g = qkv + (rowB + j * 64 + n) * F + 4096 + kvh * 128 + (sgc ^ (n & 7)) * 8;
      gload_lds16(g, kd + p * 4096);
      gload_lds16(vs + p * 2048, vd + p * 4096);
    }
  };

  for (int half = 0; half < 2; ++half) {
    const int t = half ? 15 - pair : pair;
    const int nt = 2 * t + 2;
    const int r0 = t * 128;

    bf16x8 qf[2][4];
    {
      const u16* qp = qkv + (rowB + r0 + w * 32 + l15) * F + h * 128 + l4 * 8;
#pragma unroll
      for (int m = 0; m < 2; m++)
#pragma unroll
        for (int kk = 0; kk < 4; kk++)
          qf[m][kk] = *reinterpret_cast<const bf16x8*>(qp + (size_t)m * 16 * F + kk * 32);
    }

    f32x4 acco[2][8] = {};
    float m_r[2][4], l_r[2][4];
#pragma unroll
    for (int m = 0; m < 2; m++)
#pragma unroll
      for (int r = 0; r < 4; r++) { m_r[m][r] = -1e30f; l_r[m][r] = 0.f; }

    stage(0, 0);
    __syncthreads();

    for (int j = 0; j < nt; ++j) {
      const int cur = j & 1;
      if (j + 1 < nt) stage(j + 1, cur ^ 1);

      const char* kbase = ((const char*)Kt) + cur * 16384;
      f32x4 accs[2][4] = {};
      __builtin_amdgcn_s_setprio(1);
#pragma unroll
      for (int ns = 0; ns < 4; ns++) {
        int n = ns * 16 + l15;
        const char* kb = kbase + n * 256;
#pragma unroll
        for (int kk = 0; kk < 4; kk++) {
          bf16x8 kf = *reinterpret_cast<const bf16x8*>(kb + (((kk * 4 + l4) ^ (n & 7)) << 4));
          accs[0][ns] = __builtin_amdgcn_mfma_f32_16x16x32_bf16(qf[0][kk], kf, accs[0][ns], 0, 0, 0);
          accs[1][ns] = __builtin_amdgcn_mfma_f32_16x16x32_bf16(qf[1][kk], kf, accs[1][ns], 0, 0, 0);
        }
      }
      __builtin_amdgcn_s_setprio(0);

      const int qb = r0 + w * 32 + l4 * 4;
      const int kvb = j * 64 + l15;
      if (j >= 2 * t) {
#pragma unroll
        for (int m = 0; m < 2; m++)
#pragma unroll
          for (int ns = 0; ns < 4; ns++)
#pragma unroll
            for (int r = 0; r < 4; r++)
              accs[m][ns][r] = (kvb + ns * 16 > qb + m * 16 + r) ? -1e30f : accs[m][ns][r] * sc;
      } else {
#pragma unroll
        for (int m = 0; m < 2; m++)
#pragma unroll
          for (int ns = 0; ns < 4; ns++)
#pragma unroll
            for (int r = 0; r < 4; r++) accs[m][ns][r] *= sc;
      }

      float tm[2][4];
#pragma unroll
      for (int m = 0; m < 2; m++)
#pragma unroll
        for (int r = 0; r < 4; r++) {
          float a = fmaxf(fmaxf(accs[m][0][r], accs[m][1][r]), fmaxf(accs[m][2][r], accs[m][3][r]));
          a = fmaxf(a, __shfl_xor(a, 1));
          a = fmaxf(a, __shfl_xor(a, 2));
          a = fmaxf(a, __shfl_xor(a, 4));
          a = fmaxf(a, __shfl_xor(a, 8));
          tm[m][r] = a;
        }
      int needb = 0;
#pragma unroll
      for (int m = 0; m < 2; m++)
#pragma unroll
        for (int r = 0; r < 4; r++) needb |= (tm[m][r] > m_r[m][r] + 8.0f) ? 1 : 0;
      if (__any(needb)) {
#pragma unroll
        for (int m = 0; m < 2; m++)
#pragma unroll
          for (int r = 0; r < 4; r++) {
            float m2 = fmaxf(m_r[m][r], tm[m][r]);
            float fr = exp2f(m_r[m][r] - m2);
            m_r[m][r] = m2;
            l_r[m][r] *= fr;
#pragma unroll
            for (int ns = 0; ns < 8; ns++) acco[m][ns][r] *= fr;
          }
      }
      float ps[2][4] = {};
#pragma unroll
      for (int m = 0; m < 2; m++)
#pragma unroll
        for (int ns = 0; ns < 4; ns++)
#pragma unroll
          for (int r = 0; r < 4; r++) {
            float p = exp2f(accs[m][ns][r] - m_r[m][r]);
            ps[m][r] += p;
            int row = m * 16 + l4 * 4 + r;
            int kv2 = (ns * 16 + l15) * 2;
            *(u16*)(PlW + row * 128 + (kv2 ^ ((row & 7) << 4))) = f2bf(p);
          }
#pragma unroll
      for (int m = 0; m < 2; m++)
#pragma unroll
        for (int r = 0; r < 4; r++) {
          float s2 = ps[m][r];
          s2 += __shfl_xor(s2, 1);
          s2 += __shfl_xor(s2, 2);
          s2 += __shfl_xor(s2, 4);
          s2 += __shfl_xor(s2, 8);
          l_r[m][r] += s2;
        }

      const char* vbase = ((const char*)Vt) + cur * 16384;
      bf16x8 pf[2][2];
#pragma unroll
      for (int m = 0; m < 2; m++)
#pragma unroll
        for (int kk = 0; kk < 2; kk++) {
          int row = m * 16 + l15;
          pf[m][kk] = *reinterpret_cast<const bf16x8*>(PlW + row * 128 + (((kk * 4 + l4) ^ (row & 7)) << 4));
        }
      __builtin_amdgcn_s_setprio(1);
#pragma unroll
      for (int ns = 0; ns < 8; ns++) {
        int d = ns * 16 + l15;
        const char* vb = vbase + d * 128;
#pragma unroll
        for (int kk = 0; kk < 2; kk++) {
          bf16x8 vf = *reinterpret_cast<const bf16x8*>(vb + (((kk * 4 + l4) ^ (d & 7)) << 4));
          acco[0][ns] = __builtin_amdgcn_mfma_f32_16x16x32_bf16(pf[0][kk], vf, acco[0][ns], 0, 0, 0);
          acco[1][ns] = __builtin_amdgcn_mfma_f32_16x16x32_bf16(pf[1][kk], vf, acco[1][ns], 0, 0, 0);
        }
      }
      __builtin_amdgcn_s_setprio(0);

      __syncthreads();
    }

#pragma unroll
    for (int m = 0; m < 2; m++)
#pragma unroll
      for (int r = 0; r < 4; r++) {
        float inv = 1.f / l_r[m][r];
        size_t row = rowB + r0 + w * 32 + m * 16 + l4 * 4 + r;
#pragma unroll
        for (int ns = 0; ns < 8; ns++)
          out[row * E + h * 128 + ns * 16 + l15] = f2bf(acco[m][ns][r] * inv);
      }
  }
}

extern "C" void kernel_launch(void* const* d_in, const int* in_sizes, int n_in,
                              void* d_out, int out_size, void* d_ws, size_t ws_size,
                              hipStream_t stream) {
  const float* x = (const float*)d_in[0];
  const float* w_in = (const float*)d_in[1];
  const float* w_out = (const float*)d_in[2];
  float* out = (float*)d_out;
  char* ws = (char*)d_ws;

  u16* xb = (u16*)(ws);                                   // 33,554,432 B (reused as attn out)
  u16* wib = (u16*)(ws + 33554432ull);                    // 50,331,648 B (reused as V^T images)
  u16* wob = (u16*)(ws + 83886080ull);                    // 33,554,432 B
  u16* qkvb = (u16*)(ws + 117440512ull);                  // 50,331,648 B
  float* ct = (float*)(ws + 167772160ull);                // 524,288 B
  float* st = ct + 2048 * 64;                             // 524,288 B
  u16* attnb = xb;
  u16* vtg = wib;

  cvt_bf16<<<8192, 256, 0, stream>>>(x, xb, 16777216);
  cvt_bf16<<<12288, 256, 0, stream>>>(w_in, wib, 25165824);
  cvt_bf16<<<8192, 256, 0, stream>>>(w_out, wob, 16777216);
  rope_table<<<512, 256, 0, stream>>>(ct, st);
  gemm256<u16><<<384, 512, 0, stream>>>(xb, wib, qkvb, 4096, 6144, 4096);
  rope_apply<<<5120, 256, 0, stream>>>(qkvb, ct, st);
  prep_vt<<<512, 256, 0, stream>>>(qkvb, vtg);
  attn_fwd<<<dim3(8, 64), 256, 0, stream>>>(qkvb, vtg, attnb);
  gemm256<float><<<256, 512, 0, stream>>>(attnb, wob, out, 4096, 4096, 4096);
}

// Round 6
// 570.675 us; speedup vs baseline: 1.5899x; 1.0544x over previous
//
#include <hip/hip_runtime.h>
#include <hip/hip_bf16.h>
#include <stdint.h>

typedef unsigned short u16;
typedef __bf16 bf16x8 __attribute__((ext_vector_type(8)));
typedef u16 u16x8 __attribute__((ext_vector_type(8)));
typedef float f32x4 __attribute__((ext_vector_type(4)));

#define DEV __device__ __forceinline__
#define SBAR() asm volatile("s_barrier" ::: "memory")

DEV u16 f2bf(float f) {
  uint32_t u = __builtin_bit_cast(uint32_t, f);
  return (u16)((u + 0x7FFFu + ((u >> 16) & 1u)) >> 16);
}
DEV float bf2f(u16 h) { return __builtin_bit_cast(float, (uint32_t)h << 16); }

DEV void gload_lds16(const void* g, void* l) {
  __builtin_amdgcn_global_load_lds((const __attribute__((address_space(1))) uint32_t*)g,
                                   (__attribute__((address_space(3))) uint32_t*)l, 16, 0, 0);
}

// ---------------- elementwise f32 -> bf16 cast ----------------
__global__ void cvt_bf16(const float* __restrict__ in, u16* __restrict__ out, int n) {
  int i = (blockIdx.x * 256 + threadIdx.x) * 8;
  if (i >= n) return;
  const float4* p = reinterpret_cast<const float4*>(in + i);
  float4 a = p[0], b = p[1];
  u16x8 o;
  o[0] = f2bf(a.x); o[1] = f2bf(a.y); o[2] = f2bf(a.z); o[3] = f2bf(a.w);
  o[4] = f2bf(b.x); o[5] = f2bf(b.y); o[6] = f2bf(b.z); o[7] = f2bf(b.w);
  *reinterpret_cast<u16x8*>(out + i) = o;
}

// ---------------- RoPE cos/sin table (S=2048, 64 pairs) ----------------
__global__ void rope_table(float* __restrict__ ct, float* __restrict__ st) {
  int i = blockIdx.x * 256 + threadIdx.x;  // S*64 total
  int s = i >> 6, d = i & 63;
  float invf = powf(10000.0f, -(float)d * (1.0f / 64.0f));
  float ang = (float)s * invf;
  ct[i] = cosf(ang);
  st[i] = sinf(ang);
}

// ---------------- RoPE applied in-place on bf16 qkv ----------------
__global__ void rope_apply(u16* __restrict__ qkv, const float* __restrict__ ct, const float* __restrict__ st) {
  int idx = blockIdx.x * 256 + threadIdx.x;
  int grp = idx & 7;
  int head = (idx >> 3) % 40;
  int row = idx / 320;
  int s = row & 2047;
  size_t f0 = head < 32 ? (size_t)head * 128 : (size_t)4096 + (size_t)(head - 32) * 128;
  u16* p = qkv + (size_t)row * 6144 + f0 + grp * 8;
  u16x8 a = *reinterpret_cast<const u16x8*>(p);
  u16x8 b = *reinterpret_cast<const u16x8*>(p + 64);
  const float4* cp = reinterpret_cast<const float4*>(ct + s * 64 + grp * 8);
  const float4* sp = reinterpret_cast<const float4*>(st + s * 64 + grp * 8);
  float4 c0 = cp[0], c1 = cp[1], s0 = sp[0], s1 = sp[1];
  float cc[8] = {c0.x, c0.y, c0.z, c0.w, c1.x, c1.y, c1.z, c1.w};
  float ss[8] = {s0.x, s0.y, s0.z, s0.w, s1.x, s1.y, s1.z, s1.w};
  u16x8 o1, o2;
#pragma unroll
  for (int i = 0; i < 8; i++) {
    float x1 = bf2f(a[i]), x2 = bf2f(b[i]);
    o1[i] = f2bf(x1 * cc[i] - x2 * ss[i]);
    o2[i] = f2bf(x2 * cc[i] + x1 * ss[i]);
  }
  *reinterpret_cast<u16x8*>(p) = o1;
  *reinterpret_cast<u16x8*>(p + 64) = o2;
}

// ---------------- V^T tile image prep ----------------
__global__ void prep_vt(const u16* __restrict__ qkv, u16* __restrict__ vtg) {
  int id = blockIdx.x;  // (b*8+kvh)*32 + j
  int j = id & 31, kvh = (id >> 5) & 7, b = id >> 8;
  const int tid = threadIdx.x;
  const size_t rowB = (size_t)b * 2048;
  u16* img = vtg + (size_t)id * 8192;
#pragma unroll
  for (int p = 0; p < 4; p++) {
    int lin = p * 256 + tid;
    int d = lin >> 3, c = lin & 7;
    const u16* src = qkv + (rowB + j * 64 + c * 8) * 6144 + 5120 + kvh * 128 + d;
    u16x8 v;
#pragma unroll
    for (int i = 0; i < 8; i++) v[i] = src[(size_t)i * 6144];
    *reinterpret_cast<u16x8*>(img + d * 64 + ((c ^ (d & 7)) << 3)) = v;
  }
}

// ---------------- GEMM epilogue store helpers ----------------
DEV void store_c(float* C, size_t idx, float v) { C[idx] = v; }
DEV void store_c(u16* C, size_t idx, float v) { C[idx] = f2bf(v); }

// ---------------- 256x256 8-phase GEMM: C[M][N] = A[M][K] * B[N][K]^T (C stride ldc) ----------------
// LDS: A buf0 [0,32K) buf1 [32K,64K); B buf0 [64K,96K) buf1 [96K,128K).
// Tile image: 256 rows x 64 cols bf16, row stride 128B; slot' = slot ^ (row&7).
// Hazards: A0:P3, A1:P3, B0:P2, B1:P2. Stages: P1 A1(t+1)->other; P3 B0(t+2); P4 A0(t+2),B1(t+2).
template <typename OutT>
__global__ __launch_bounds__(512, 2) void gemm256(const u16* __restrict__ A, const u16* __restrict__ B,
                                                  OutT* __restrict__ C, int M, int N, int K, int ldc) {
  __shared__ __align__(16) u16 lds[65536];  // 128 KiB
  char* LB = (char*)lds;
  const int tid = threadIdx.x;
  const int w = tid >> 6, lane = tid & 63;
  const int l15 = lane & 15, l4 = lane >> 4;
  const int wm = w >> 2, wn = w & 3;

  int nwg = gridDim.x;
  int q = nwg >> 3, rr = nwg & 7;
  int xcd = blockIdx.x & 7, idx = blockIdx.x >> 3;
  int sw = (xcd < rr ? xcd * (q + 1) : rr * (q + 1) + (xcd - rr) * q) + idx;
  int gxn = N >> 8;
  int by = sw / gxn, bx = sw - by * gxn;
  const int row0 = by << 8, col0 = bx << 8;
  const int NT = K >> 6;

  const int srow = w * 8 + (lane >> 3);
  const int sc16 = (lane & 7) ^ ((lane >> 3) & 7);
  const u16* gA = A + (size_t)(row0 + srow) * K + sc16 * 8;
  const u16* gB = B + (size_t)(col0 + srow) * K + sc16 * 8;

  const int fl = (l15 & 7) << 4;
  const int aoff = (wm * 128 + l15) * 128 + l4 * 16;
  const int boff = (wn * 64 + l15) * 128 + l4 * 16;

  f32x4 acc[8][4] = {};
  bf16x8 fA[4][2], fB0[2][2], fBc[2][2];

#define STAGE_A(kt, h, base)                                                      \
  {                                                                               \
    const u16* g_ = gA + (size_t)((h)*128) * K + (size_t)(kt)*64;                 \
    gload_lds16(g_, (base) + (h)*16384 + w * 1024);                               \
    gload_lds16(g_ + (size_t)64 * K, (base) + (h)*16384 + 8192 + w * 1024);       \
  }
#define STAGE_B(kt, h, base)                                                      \
  {                                                                               \
    const u16* g_ = gB + (size_t)((h)*128) * K + (size_t)(kt)*64;                 \
    gload_lds16(g_, (base) + (h)*16384 + w * 1024);                               \
    gload_lds16(g_ + (size_t)64 * K, (base) + (h)*16384 + 8192 + w * 1024);       \
  }
#define MFMA_Q(FB, MH, NH)                                                        \
  _Pragma("unroll") for (int kk = 0; kk < 2; kk++) {                              \
    _Pragma("unroll") for (int mf = 0; mf < 4; mf++) {                            \
      _Pragma("unroll") for (int nf = 0; nf < 2; nf++) {                          \
        acc[(MH)*4 + mf][(NH)*2 + nf] = __builtin_amdgcn_mfma_f32_16x16x32_bf16(  \
            fA[mf][kk], FB[nf][kk], acc[(MH)*4 + mf][(NH)*2 + nf], 0, 0, 0);      \
      }                                                                           \
    }                                                                             \
  }

  STAGE_A(0, 0, LB);
  STAGE_A(0, 1, LB);
  STAGE_B(0, 0, LB + 65536);
  STAGE_B(0, 1, LB + 65536);
  STAGE_A(1, 0, LB + 32768);
  STAGE_B(1, 0, LB + 98304);
  STAGE_B(1, 1, LB + 98304);
  asm volatile("s_waitcnt vmcnt(6)" ::: "memory");
  SBAR();

  for (int t = 0; t < NT; ++t) {
    char* ac = LB + (t & 1) * 32768;
    char* bc = LB + 65536 + (t & 1) * 32768;
    char* an = LB + ((t + 1) & 1) * 32768;

    // ---- P1 ----
#pragma unroll
    for (int mf = 0; mf < 4; mf++)
#pragma unroll
      for (int kk = 0; kk < 2; kk++)
        fA[mf][kk] = *(const bf16x8*)(ac + ((aoff + mf * 2048 + kk * 64) ^ fl));
#pragma unroll
    for (int nf = 0; nf < 2; nf++)
#pragma unroll
      for (int kk = 0; kk < 2; kk++)
        fB0[nf][kk] = *(const bf16x8*)(bc + ((boff + nf * 2048 + kk * 64) ^ fl));
    if (t + 1 < NT) STAGE_A(t + 1, 1, an);
    asm volatile("s_waitcnt lgkmcnt(8)" ::: "memory");
    SBAR();
    asm volatile("s_waitcnt lgkmcnt(0)" ::: "memory");
    __builtin_amdgcn_sched_barrier(0);
    __builtin_amdgcn_s_setprio(1);
    MFMA_Q(fB0, 0, 0);
    __builtin_amdgcn_s_setprio(0);
    SBAR();

    // ---- P2 ----
#pragma unroll
    for (int nf = 0; nf < 2; nf++)
#pragma unroll
      for (int kk = 0; kk < 2; kk++)
        fBc[nf][kk] = *(const bf16x8*)(bc + ((boff + (nf + 2) * 2048 + kk * 64) ^ fl));
    SBAR();
    asm volatile("s_waitcnt lgkmcnt(0)" ::: "memory");
    __builtin_amdgcn_sched_barrier(0);
    __builtin_amdgcn_s_setprio(1);
    MFMA_Q(fBc, 0, 1);
    __builtin_amdgcn_s_setprio(0);
    SBAR();

    // ---- P3 ----
#pragma unroll
    for (int mf = 0; mf < 4; mf++)
#pragma unroll
      for (int kk = 0; kk < 2; kk++)
        fA[mf][kk] = *(const bf16x8*)(ac + ((aoff + (mf + 4) * 2048 + kk * 64) ^ fl));
    if (t + 2 < NT) STAGE_B(t + 2, 0, bc);
    SBAR();
    asm volatile("s_waitcnt lgkmcnt(0)" ::: "memory");
    __builtin_amdgcn_sched_barrier(0);
    __builtin_amdgcn_s_setprio(1);
    MFMA_Q(fBc, 1, 1);
    __builtin_amdgcn_s_setprio(0);
    SBAR();

    // ---- P4 ----
    if (t + 2 < NT) {
      STAGE_A(t + 2, 0, ac);
      STAGE_B(t + 2, 1, bc);
    }
    SBAR();
    __builtin_amdgcn_s_setprio(1);
    MFMA_Q(fB0, 1, 0);
    __builtin_amdgcn_s_setprio(0);
    if (t <= NT - 3) {
      asm volatile("s_waitcnt vmcnt(6)" ::: "memory");
      SBAR();
    } else if (t < NT - 1) {
      asm volatile("s_waitcnt vmcnt(0)" ::: "memory");
      SBAR();
    }
  }

#pragma unroll
  for (int mf = 0; mf < 8; mf++)
#pragma unroll
    for (int nf = 0; nf < 4; nf++)
#pragma unroll
      for (int r = 0; r < 4; r++) {
        size_t row = (size_t)row0 + wm * 128 + mf * 16 + l4 * 4 + r;
        size_t col = (size_t)col0 + wn * 64 + nf * 16 + l15;
        store_c(C, row * (size_t)ldc + col, acc[mf][nf][r]);
      }
#undef STAGE_A
#undef STAGE_B
#undef MFMA_Q
}

// ---------------- 256x128 2-phase GEMM (tail-free partner for gemm1's K/V columns) ----------------
// LDS: A buf0 [0,32K) buf1 [32K,64K); B buf0 [64K,80K) buf1 [80K,96K).
// Hazards: A0 read P1 -> staged P2; A1 read P2 -> staged P1(t) into other buf; B read P1 -> staged P2.
// FIFO/tile: P1 issues A1(t+1) [2 gloads]; P2 issues A0(t+2),B(t+2) [4]. Boundary vmcnt(4).
__global__ __launch_bounds__(512, 2) void gemm_bn128(const u16* __restrict__ A, const u16* __restrict__ B,
                                                     u16* __restrict__ C, int M, int N, int K, int ldc) {
  __shared__ __align__(16) u16 lds[49152];  // 96 KiB
  char* LB = (char*)lds;
  const int tid = threadIdx.x;
  const int w = tid >> 6, lane = tid & 63;
  const int l15 = lane & 15, l4 = lane >> 4;
  const int wm = w >> 2, wn = w & 3;

  int nwg = gridDim.x;
  int q = nwg >> 3, rr = nwg & 7;
  int xcd = blockIdx.x & 7, idx = blockIdx.x >> 3;
  int sw = (xcd < rr ? xcd * (q + 1) : rr * (q + 1) + (xcd - rr) * q) + idx;
  int gxn = N >> 7;
  int by = sw / gxn, bx = sw - by * gxn;
  const int row0 = by << 8, col0 = bx << 7;
  const int NT = K >> 6;

  const int srow = w * 8 + (lane >> 3);
  const int sc16 = (lane & 7) ^ ((lane >> 3) & 7);
  const u16* gA = A + (size_t)(row0 + srow) * K + sc16 * 8;
  const u16* gB = B + (size_t)(col0 + srow) * K + sc16 * 8;

  const int fl = (l15 & 7) << 4;
  const int aoff = (wm * 128 + l15) * 128 + l4 * 16;
  const int boff = (wn * 32 + l15) * 128 + l4 * 16;

  f32x4 acc[8][2] = {};
  bf16x8 fA[4][2], fB[2][2];

#define STAGE_A(kt, h, base)                                                      \
  {                                                                               \
    const u16* g_ = gA + (size_t)((h)*128) * K + (size_t)(kt)*64;                 \
    gload_lds16(g_, (base) + (h)*16384 + w * 1024);                               \
    gload_lds16(g_ + (size_t)64 * K, (base) + (h)*16384 + 8192 + w * 1024);       \
  }
#define STAGE_B(kt, base)                                                         \
  {                                                                               \
    const u16* g_ = gB + (size_t)(kt)*64;                                         \
    gload_lds16(g_, (base) + w * 1024);                                           \
    gload_lds16(g_ + (size_t)64 * K, (base) + 8192 + w * 1024);                   \
  }

  // prologue: tile0 {A0,A1,B} -> buf0; tile1 {A0,B} -> buf1 (A1(1) staged at t=0 P1)
  STAGE_A(0, 0, LB);
  STAGE_A(0, 1, LB);
  STAGE_B(0, LB + 65536);
  STAGE_A(1, 0, LB + 32768);
  STAGE_B(1, LB + 65536 + 16384);
  asm volatile("s_waitcnt vmcnt(4)" ::: "memory");
  SBAR();

  for (int t = 0; t < NT; ++t) {
    char* ac = LB + (t & 1) * 32768;
    char* bc = LB + 65536 + (t & 1) * 16384;
    char* an = LB + ((t + 1) & 1) * 32768;

    // ---- P1: read A-h0 (8) + B (4); stage A1(t+1) -> other buf; MFMA mf0-3 ----
#pragma unroll
    for (int mf = 0; mf < 4; mf++)
#pragma unroll
      for (int kk = 0; kk < 2; kk++)
        fA[mf][kk] = *(const bf16x8*)(ac + ((aoff + mf * 2048 + kk * 64) ^ fl));
#pragma unroll
    for (int nf = 0; nf < 2; nf++)
#pragma unroll
      for (int kk = 0; kk < 2; kk++)
        fB[nf][kk] = *(const bf16x8*)(bc + ((boff + nf * 2048 + kk * 64) ^ fl));
    if (t + 1 < NT) STAGE_A(t + 1, 1, an);
    asm volatile("s_waitcnt lgkmcnt(8)" ::: "memory");
    SBAR();
    asm volatile("s_waitcnt lgkmcnt(0)" ::: "memory");
    __builtin_amdgcn_sched_barrier(0);
    __builtin_amdgcn_s_setprio(1);
#pragma unroll
    for (int kk = 0; kk < 2; kk++)
#pragma unroll
      for (int mf = 0; mf < 4; mf++)
#pragma unroll
        for (int nf = 0; nf < 2; nf++)
          acc[mf][nf] = __builtin_amdgcn_mfma_f32_16x16x32_bf16(fA[mf][kk], fB[nf][kk], acc[mf][nf], 0, 0, 0);
    __builtin_amdgcn_s_setprio(0);
    SBAR();

    // ---- P2: read A-h1 (8); stage A0(t+2), B(t+2) -> current buf; MFMA mf4-7 ----
#pragma unroll
    for (int mf = 0; mf < 4; mf++)
#pragma unroll
      for (int kk = 0; kk < 2; kk++)
        fA[mf][kk] = *(const bf16x8*)(ac + ((aoff + (mf + 4) * 2048 + kk * 64) ^ fl));
    if (t + 2 < NT) {
      STAGE_A(t + 2, 0, ac);
      STAGE_B(t + 2, bc);
    }
    SBAR();
    asm volatile("s_waitcnt lgkmcnt(0)" ::: "memory");
    __builtin_amdgcn_sched_barrier(0);
    __builtin_amdgcn_s_setprio(1);
#pragma unroll
    for (int kk = 0; kk < 2; kk++)
#pragma unroll
      for (int mf = 0; mf < 4; mf++)
#pragma unroll
        for (int nf = 0; nf < 2; nf++)
          acc[mf + 4][nf] = __builtin_amdgcn_mfma_f32_16x16x32_bf16(fA[mf][kk], fB[nf][kk], acc[mf + 4][nf], 0, 0, 0);
    __builtin_amdgcn_s_setprio(0);
    // boundary: counted vmcnt keeps {A0,B of t+2} (4 loads), forces all of t+1
    if (t <= NT - 3) {
      asm volatile("s_waitcnt vmcnt(4)" ::: "memory");
      SBAR();
    } else if (t < NT - 1) {
      asm volatile("s_waitcnt vmcnt(0)" ::: "memory");
      SBAR();
    }
  }

#pragma unroll
  for (int mf = 0; mf < 8; mf++)
#pragma unroll
    for (int nf = 0; nf < 2; nf++)
#pragma unroll
      for (int r = 0; r < 4; r++) {
        size_t row = (size_t)row0 + wm * 128 + mf * 16 + l4 * 4 + r;
        size_t col = (size_t)col0 + wn * 32 + nf * 16 + l15;
        C[row * (size_t)ldc + col] = f2bf(acc[mf][nf][r]);
      }
#undef STAGE_A
#undef STAGE_B
}

// ---------------- causal GQA flash attention (unchanged, round-2 proven) ----------------
__global__ __launch_bounds__(256, 2) void attn_fwd(const u16* __restrict__ qkv,
                                                   const u16* __restrict__ vtg,
                                                   u16* __restrict__ out) {
  constexpr int S = 2048, F = 6144, E = 4096;
  __shared__ __align__(16) u16 Kt[2 * 8192];
  __shared__ __align__(16) u16 Vt[2 * 8192];
  __shared__ __align__(16) u16 Pl[4 * 2048];

  const int tid = threadIdx.x;
  const int w = tid >> 6, lane = tid & 63;
  const int l15 = lane & 15, l4 = lane >> 4;
  const int pair = blockIdx.x;  // 0..7
  const int b = blockIdx.y >> 5, h = blockIdx.y & 31, kvh = h >> 2;
  const size_t rowB = (size_t)b * S;
  const float sc = 0.08838834764831845f * 1.4426950408889634f;
  const int sgn = tid >> 4, sgc = tid & 15;
  char* PlW = ((char*)Pl) + w * 4096;
  const size_t vtb = (size_t)(b * 8 + kvh) * 32 * 8192;

  auto stage = [&](int j, int buf) {
    char* kd = ((char*)Kt) + buf * 16384 + w * 1024;
    char* vd = ((char*)Vt) + buf * 16384 + w * 1024;
    const u16* vs = vtg + vtb + (size_t)j * 8192 + tid * 8;
#pragma unroll
    for (int p = 0; p < 4; p++) {
      int n = p * 16 + sgn;
      const u16* g = qkv + (rowB + j * 64 + n) * F + 4096 + kvh * 128 + (sgc ^ (n & 7)) * 8;
      gload_lds16(g, kd + p * 4096);
      gload_lds16(vs + p * 2048, vd + p * 4096);
    }
  };

  for (int half = 0; half < 2; ++half) {
    const int t = half ? 15 - pair : pair;
    const int nt = 2 * t + 2;
    const int r0 = t * 128;

    bf16x8 qf[2][4];
    {
      const u16* qp = qkv + (rowB + r0 + w * 32 + l15) * F + h * 128 + l4 * 8;
#pragma unroll
      for (int m = 0; m < 2; m++)
#pragma unroll
        for (int kk = 0; kk < 4; kk++)
          qf[m][kk] = *reinterpret_cast<const bf16x8*>(qp + (size_t)m * 16 * F + kk * 32);
    }

    f32x4 acco[2][8] = {};
    float m_r[2][4], l_r[2][4];
#pragma unroll
    for (int m = 0; m < 2; m++)
#pragma unroll
      for (int r = 0; r < 4; r++) { m_r[m][r] = -1e30f; l_r[m][r] = 0.f; }

    stage(0, 0);
    __syncthreads();

    for (int j = 0; j < nt; ++j) {
      const int cur = j & 1;
      if (j + 1 < nt) stage(j + 1, cur ^ 1);

      const char* kbase = ((const char*)Kt) + cur * 16384;
      f32x4 accs[2][4] = {};
      __builtin_amdgcn_s_setprio(1);
#pragma unroll
      for (int ns = 0; ns < 4; ns++) {
        int n = ns * 16 + l15;
        const char* kb = kbase + n * 256;
#pragma unroll
        for (int kk = 0; kk < 4; kk++) {
          bf16x8 kf = *reinterpret_cast<const bf16x8*>(kb + (((kk * 4 + l4) ^ (n & 7)) << 4));
          accs[0][ns] = __builtin_amdgcn_mfma_f32_16x16x32_bf16(qf[0][kk], kf, accs[0][ns], 0, 0, 0);
          accs[1][ns] = __builtin_amdgcn_mfma_f32_16x16x32_bf16(qf[1][kk], kf, accs[1][ns], 0, 0, 0);
        }
      }
      __builtin_amdgcn_s_setprio(0);

      const int qb = r0 + w * 32 + l4 * 4;
      const int kvb = j * 64 + l15;
      if (j >= 2 * t) {
#pragma unroll
        for (int m = 0; m < 2; m++)
#pragma unroll
          for (int ns = 0; ns < 4; ns++)
#pragma unroll
            for (int r = 0; r < 4; r++)
              accs[m][ns][r] = (kvb + ns * 16 > qb + m * 16 + r) ? -1e30f : accs[m][ns][r] * sc;
      } else {
#pragma unroll
        for (int m = 0; m < 2; m++)
#pragma unroll
          for (int ns = 0; ns < 4; ns++)
#pragma unroll
            for (int r = 0; r < 4; r++) accs[m][ns][r] *= sc;
      }

      float tm[2][4];
#pragma unroll
      for (int m = 0; m < 2; m++)
#pragma unroll
        for (int r = 0; r < 4; r++) {
          float a = fmaxf(fmaxf(accs[m][0][r], accs[m][1][r]), fmaxf(accs[m][2][r], accs[m][3][r]));
          a = fmaxf(a, __shfl_xor(a, 1));
          a = fmaxf(a, __shfl_xor(a, 2));
          a = fmaxf(a, __shfl_xor(a, 4));
          a = fmaxf(a, __shfl_xor(a, 8));
          tm[m][r] = a;
        }
      int needb = 0;
#pragma unroll
      for (int m = 0; m < 2; m++)
#pragma unroll
        for (int r = 0; r < 4; r++) needb |= (tm[m][r] > m_r[m][r] + 8.0f) ? 1 : 0;
      if (__any(needb)) {
#pragma unroll
        for (int m = 0; m < 2; m++)
#pragma unroll
          for (int r = 0; r < 4; r++) {
            float m2 = fmaxf(m_r[m][r], tm[m][r]);
            float fr = exp2f(m_r[m][r] - m2);
            m_r[m][r] = m2;
            l_r[m][r] *= fr;
#pragma unroll
            for (int ns = 0; ns < 8; ns++) acco[m][ns][r] *= fr;
          }
      }
      float ps[2][4] = {};
#pragma unroll
      for (int m = 0; m < 2; m++)
#pragma unroll
        for (int ns = 0; ns < 4; ns++)
#pragma unroll
          for (int r = 0; r < 4; r++) {
            float p = exp2f(accs[m][ns][r] - m_r[m][r]);
            ps[m][r] += p;
            int row = m * 16 + l4 * 4 + r;
            int kv2 = (ns * 16 + l15) * 2;
            *(u16*)(PlW + row * 128 + (kv2 ^ ((row & 7) << 4))) = f2bf(p);
          }
#pragma unroll
      for (int m = 0; m < 2; m++)
#pragma unroll
        for (int r = 0; r < 4; r++) {
          float s2 = ps[m][r];
          s2 += __shfl_xor(s2, 1);
          s2 += __shfl_xor(s2, 2);
          s2 += __shfl_xor(s2, 4);
          s2 += __shfl_xor(s2, 8);
          l_r[m][r] += s2;
        }

      const char* vbase = ((const char*)Vt) + cur * 16384;
      bf16x8 pf[2][2];
#pragma unroll
      for (int m = 0; m < 2; m++)
#pragma unroll
        for (int kk = 0; kk < 2; kk++) {
          int row = m * 16 + l15;
          pf[m][kk] = *reinterpret_cast<const bf16x8*>(PlW + row * 128 + (((kk * 4 + l4) ^ (row & 7)) << 4));
        }
      __builtin_amdgcn_s_setprio(1);
#pragma unroll
      for (int ns = 0; ns < 8; ns++) {
        int d = ns * 16 + l15;
        const char* vb = vbase + d * 128;
#pragma unroll
        for (int kk = 0; kk < 2; kk++) {
          bf16x8 vf = *reinterpret_cast<const bf16x8*>(vb + (((kk * 4 + l4) ^ (d & 7)) << 4));
          acco[0][ns] = __builtin_amdgcn_mfma_f32_16x16x32_bf16(pf[0][kk], vf, acco[0][ns], 0, 0, 0);
          acco[1][ns] = __builtin_amdgcn_mfma_f32_16x16x32_bf16(pf[1][kk], vf, acco[1][ns], 0, 0, 0);
        }
      }
      __builtin_amdgcn_s_setprio(0);

      __syncthreads();
    }

#pragma unroll
    for (int m = 0; m < 2; m++)
#pragma unroll
      for (int r = 0; r < 4; r++) {
        float inv = 1.f / l_r[m][r];
        size_t row = rowB + r0 + w * 32 + m * 16 + l4 * 4 + r;
#pragma unroll
        for (int ns = 0; ns < 8; ns++)
          out[row * E + h * 128 + ns * 16 + l15] = f2bf(acco[m][ns][r] * inv);
      }
  }
}

extern "C" void kernel_launch(void* const* d_in, const int* in_sizes, int n_in,
                              void* d_out, int out_size, void* d_ws, size_t ws_size,
                              hipStream_t stream) {
  const float* x = (const float*)d_in[0];
  const float* w_in = (const float*)d_in[1];
  const float* w_out = (const float*)d_in[2];
  float* out = (float*)d_out;
  char* ws = (char*)d_ws;

  u16* xb = (u16*)(ws);                                   // 33,554,432 B (reused as attn out)
  u16* wib = (u16*)(ws + 33554432ull);                    // 50,331,648 B (reused as V^T images)
  u16* wob = (u16*)(ws + 83886080ull);                    // 33,554,432 B
  u16* qkvb = (u16*)(ws + 117440512ull);                  // 50,331,648 B
  float* ct = (float*)(ws + 167772160ull);                // 524,288 B
  float* st = ct + 2048 * 64;                             // 524,288 B
  u16* attnb = xb;
  u16* vtg = wib;

  cvt_bf16<<<8192, 256, 0, stream>>>(x, xb, 16777216);
  cvt_bf16<<<12288, 256, 0, stream>>>(w_in, wib, 25165824);
  cvt_bf16<<<8192, 256, 0, stream>>>(w_out, wob, 16777216);
  rope_table<<<512, 256, 0, stream>>>(ct, st);
  // gemm1 split into two tail-free launches (256 blocks each):
  //   L1: Q columns 0..4095 (B rows 0..4095 of w_in)
  gemm256<u16><<<256, 512, 0, stream>>>(xb, wib, qkvb, 4096, 4096, 4096, 6144);
  //   L2: K/V columns 4096..6143 (B rows 4096..6143), BN=128 grid 16x16
  gemm_bn128<<<256, 512, 0, stream>>>(xb, wib + (size_t)4096 * 4096, qkvb + 4096, 4096, 2048, 4096, 6144);
  rope_apply<<<5120, 256, 0, stream>>>(qkvb, ct, st);
  prep_vt<<<512, 256, 0, stream>>>(qkvb, vtg);
  attn_fwd<<<dim3(8, 64), 256, 0, stream>>>(qkvb, vtg, attnb);
  gemm256<float><<<256, 512, 0, stream>>>(attnb, wob, out, 4096, 4096, 4096, 4096);
}

// Round 7
// 511.109 us; speedup vs baseline: 1.7752x; 1.1165x over previous
//
#include <hip/hip_runtime.h>
#include <hip/hip_bf16.h>
#include <stdint.h>

typedef unsigned short u16;
typedef __bf16 bf16x8 __attribute__((ext_vector_type(8)));
typedef u16 u16x8 __attribute__((ext_vector_type(8)));
typedef float f32x4 __attribute__((ext_vector_type(4)));
typedef float f32x16 __attribute__((ext_vector_type(16)));
typedef uint32_t u32x4 __attribute__((ext_vector_type(4)));

#define DEV __device__ __forceinline__
#define SBAR() asm volatile("s_barrier" ::: "memory")

DEV u16 f2bf(float f) {
  uint32_t u = __builtin_bit_cast(uint32_t, f);
  return (u16)((u + 0x7FFFu + ((u >> 16) & 1u)) >> 16);
}
DEV float bf2f(u16 h) { return __builtin_bit_cast(float, (uint32_t)h << 16); }

DEV void gload_lds16(const void* g, void* l) {
  __builtin_amdgcn_global_load_lds((const __attribute__((address_space(1))) uint32_t*)g,
                                   (__attribute__((address_space(3))) uint32_t*)l, 16, 0, 0);
}

DEV uint32_t cvtpk(float lo, float hi) {
  uint32_t r;
  asm("v_cvt_pk_bf16_f32 %0, %1, %2" : "=v"(r) : "v"(lo), "v"(hi));
  return r;
}
DEV void plswap(uint32_t& a, uint32_t& b) {
  asm("v_permlane32_swap_b32 %0, %1" : "+v"(a), "+v"(b));
}

// ---------------- elementwise f32 -> bf16 cast ----------------
__global__ void cvt_bf16(const float* __restrict__ in, u16* __restrict__ out, int n) {
  int i = (blockIdx.x * 256 + threadIdx.x) * 8;
  if (i >= n) return;
  const float4* p = reinterpret_cast<const float4*>(in + i);
  float4 a = p[0], b = p[1];
  u16x8 o;
  o[0] = f2bf(a.x); o[1] = f2bf(a.y); o[2] = f2bf(a.z); o[3] = f2bf(a.w);
  o[4] = f2bf(b.x); o[5] = f2bf(b.y); o[6] = f2bf(b.z); o[7] = f2bf(b.w);
  *reinterpret_cast<u16x8*>(out + i) = o;
}

// ---------------- RoPE cos/sin table (S=2048, 64 pairs) ----------------
__global__ void rope_table(float* __restrict__ ct, float* __restrict__ st) {
  int i = blockIdx.x * 256 + threadIdx.x;
  int s = i >> 6, d = i & 63;
  float invf = powf(10000.0f, -(float)d * (1.0f / 64.0f));
  float ang = (float)s * invf;
  ct[i] = cosf(ang);
  st[i] = sinf(ang);
}

// ---------------- RoPE applied in-place on bf16 qkv ----------------
__global__ void rope_apply(u16* __restrict__ qkv, const float* __restrict__ ct, const float* __restrict__ st) {
  int idx = blockIdx.x * 256 + threadIdx.x;
  int grp = idx & 7;
  int head = (idx >> 3) % 40;
  int row = idx / 320;
  int s = row & 2047;
  size_t f0 = head < 32 ? (size_t)head * 128 : (size_t)4096 + (size_t)(head - 32) * 128;
  u16* p = qkv + (size_t)row * 6144 + f0 + grp * 8;
  u16x8 a = *reinterpret_cast<const u16x8*>(p);
  u16x8 b = *reinterpret_cast<const u16x8*>(p + 64);
  const float4* cp = reinterpret_cast<const float4*>(ct + s * 64 + grp * 8);
  const float4* sp = reinterpret_cast<const float4*>(st + s * 64 + grp * 8);
  float4 c0 = cp[0], c1 = cp[1], s0 = sp[0], s1 = sp[1];
  float cc[8] = {c0.x, c0.y, c0.z, c0.w, c1.x, c1.y, c1.z, c1.w};
  float ss[8] = {s0.x, s0.y, s0.z, s0.w, s1.x, s1.y, s1.z, s1.w};
  u16x8 o1, o2;
#pragma unroll
  for (int i = 0; i < 8; i++) {
    float x1 = bf2f(a[i]), x2 = bf2f(b[i]);
    o1[i] = f2bf(x1 * cc[i] - x2 * ss[i]);
    o2[i] = f2bf(x2 * cc[i] + x1 * ss[i]);
  }
  *reinterpret_cast<u16x8*>(p) = o1;
  *reinterpret_cast<u16x8*>(p + 64) = o2;
}

// ---------------- V^T tile image prep ----------------
__global__ void prep_vt(const u16* __restrict__ qkv, u16* __restrict__ vtg) {
  int id = blockIdx.x;  // (b*8+kvh)*32 + j
  int j = id & 31, kvh = (id >> 5) & 7, b = id >> 8;
  const int tid = threadIdx.x;
  const size_t rowB = (size_t)b * 2048;
  u16* img = vtg + (size_t)id * 8192;
#pragma unroll
  for (int p = 0; p < 4; p++) {
    int lin = p * 256 + tid;
    int d = lin >> 3, c = lin & 7;
    const u16* src = qkv + (rowB + j * 64 + c * 8) * 6144 + 5120 + kvh * 128 + d;
    u16x8 v;
#pragma unroll
    for (int i = 0; i < 8; i++) v[i] = src[(size_t)i * 6144];
    *reinterpret_cast<u16x8*>(img + d * 64 + ((c ^ (d & 7)) << 3)) = v;
  }
}

// ---------------- GEMM epilogue store helpers ----------------
DEV void store_c(float* C, size_t idx, float v) { C[idx] = v; }
DEV void store_c(u16* C, size_t idx, float v) { C[idx] = f2bf(v); }

// ---------------- 256x256 8-phase GEMM: C[M][N] = A[M][K] * B[N][K]^T (C stride ldc) ----------------
template <typename OutT>
__global__ __launch_bounds__(512, 2) void gemm256(const u16* __restrict__ A, const u16* __restrict__ B,
                                                  OutT* __restrict__ C, int M, int N, int K, int ldc) {
  __shared__ __align__(16) u16 lds[65536];  // 128 KiB
  char* LB = (char*)lds;
  const int tid = threadIdx.x;
  const int w = tid >> 6, lane = tid & 63;
  const int l15 = lane & 15, l4 = lane >> 4;
  const int wm = w >> 2, wn = w & 3;

  int nwg = gridDim.x;
  int q = nwg >> 3, rr = nwg & 7;
  int xcd = blockIdx.x & 7, idx = blockIdx.x >> 3;
  int sw = (xcd < rr ? xcd * (q + 1) : rr * (q + 1) + (xcd - rr) * q) + idx;
  int gxn = N >> 8;
  int by = sw / gxn, bx = sw - by * gxn;
  const int row0 = by << 8, col0 = bx << 8;
  const int NT = K >> 6;

  const int srow = w * 8 + (lane >> 3);
  const int sc16 = (lane & 7) ^ ((lane >> 3) & 7);
  const u16* gA = A + (size_t)(row0 + srow) * K + sc16 * 8;
  const u16* gB = B + (size_t)(col0 + srow) * K + sc16 * 8;

  const int fl = (l15 & 7) << 4;
  const int aoff = (wm * 128 + l15) * 128 + l4 * 16;
  const int boff = (wn * 64 + l15) * 128 + l4 * 16;

  f32x4 acc[8][4] = {};
  bf16x8 fA[4][2], fB0[2][2], fBc[2][2];

#define STAGE_A(kt, h, base)                                                      \
  {                                                                               \
    const u16* g_ = gA + (size_t)((h)*128) * K + (size_t)(kt)*64;                 \
    gload_lds16(g_, (base) + (h)*16384 + w * 1024);                               \
    gload_lds16(g_ + (size_t)64 * K, (base) + (h)*16384 + 8192 + w * 1024);       \
  }
#define STAGE_B(kt, h, base)                                                      \
  {                                                                               \
    const u16* g_ = gB + (size_t)((h)*128) * K + (size_t)(kt)*64;                 \
    gload_lds16(g_, (base) + (h)*16384 + w * 1024);                               \
    gload_lds16(g_ + (size_t)64 * K, (base) + (h)*16384 + 8192 + w * 1024);       \
  }
#define MFMA_Q(FB, MH, NH)                                                        \
  _Pragma("unroll") for (int kk = 0; kk < 2; kk++) {                              \
    _Pragma("unroll") for (int mf = 0; mf < 4; mf++) {                            \
      _Pragma("unroll") for (int nf = 0; nf < 2; nf++) {                          \
        acc[(MH)*4 + mf][(NH)*2 + nf] = __builtin_amdgcn_mfma_f32_16x16x32_bf16(  \
            fA[mf][kk], FB[nf][kk], acc[(MH)*4 + mf][(NH)*2 + nf], 0, 0, 0);      \
      }                                                                           \
    }                                                                             \
  }

  STAGE_A(0, 0, LB);
  STAGE_A(0, 1, LB);
  STAGE_B(0, 0, LB + 65536);
  STAGE_B(0, 1, LB + 65536);
  STAGE_A(1, 0, LB + 32768);
  STAGE_B(1, 0, LB + 98304);
  STAGE_B(1, 1, LB + 98304);
  asm volatile("s_waitcnt vmcnt(6)" ::: "memory");
  SBAR();

  for (int t = 0; t < NT; ++t) {
    char* ac = LB + (t & 1) * 32768;
    char* bc = LB + 65536 + (t & 1) * 32768;
    char* an = LB + ((t + 1) & 1) * 32768;

    // ---- P1 ----
#pragma unroll
    for (int mf = 0; mf < 4; mf++)
#pragma unroll
      for (int kk = 0; kk < 2; kk++)
        fA[mf][kk] = *(const bf16x8*)(ac + ((aoff + mf * 2048 + kk * 64) ^ fl));
#pragma unroll
    for (int nf = 0; nf < 2; nf++)
#pragma unroll
      for (int kk = 0; kk < 2; kk++)
        fB0[nf][kk] = *(const bf16x8*)(bc + ((boff + nf * 2048 + kk * 64) ^ fl));
    if (t + 1 < NT) STAGE_A(t + 1, 1, an);
    asm volatile("s_waitcnt lgkmcnt(8)" ::: "memory");
    SBAR();
    asm volatile("s_waitcnt lgkmcnt(0)" ::: "memory");
    __builtin_amdgcn_sched_barrier(0);
    __builtin_amdgcn_s_setprio(1);
    MFMA_Q(fB0, 0, 0);
    __builtin_amdgcn_s_setprio(0);
    SBAR();

    // ---- P2 ----
#pragma unroll
    for (int nf = 0; nf < 2; nf++)
#pragma unroll
      for (int kk = 0; kk < 2; kk++)
        fBc[nf][kk] = *(const bf16x8*)(bc + ((boff + (nf + 2) * 2048 + kk * 64) ^ fl));
    SBAR();
    asm volatile("s_waitcnt lgkmcnt(0)" ::: "memory");
    __builtin_amdgcn_sched_barrier(0);
    __builtin_amdgcn_s_setprio(1);
    MFMA_Q(fBc, 0, 1);
    __builtin_amdgcn_s_setprio(0);
    SBAR();

    // ---- P3 ----
#pragma unroll
    for (int mf = 0; mf < 4; mf++)
#pragma unroll
      for (int kk = 0; kk < 2; kk++)
        fA[mf][kk] = *(const bf16x8*)(ac + ((aoff + (mf + 4) * 2048 + kk * 64) ^ fl));
    if (t + 2 < NT) STAGE_B(t + 2, 0, bc);
    SBAR();
    asm volatile("s_waitcnt lgkmcnt(0)" ::: "memory");
    __builtin_amdgcn_sched_barrier(0);
    __builtin_amdgcn_s_setprio(1);
    MFMA_Q(fBc, 1, 1);
    __builtin_amdgcn_s_setprio(0);
    SBAR();

    // ---- P4 ----
    if (t + 2 < NT) {
      STAGE_A(t + 2, 0, ac);
      STAGE_B(t + 2, 1, bc);
    }
    SBAR();
    __builtin_amdgcn_s_setprio(1);
    MFMA_Q(fB0, 1, 0);
    __builtin_amdgcn_s_setprio(0);
    if (t <= NT - 3) {
      asm volatile("s_waitcnt vmcnt(6)" ::: "memory");
      SBAR();
    } else if (t < NT - 1) {
      asm volatile("s_waitcnt vmcnt(0)" ::: "memory");
      SBAR();
    }
  }

#pragma unroll
  for (int mf = 0; mf < 8; mf++)
#pragma unroll
    for (int nf = 0; nf < 4; nf++)
#pragma unroll
      for (int r = 0; r < 4; r++) {
        size_t row = (size_t)row0 + wm * 128 + mf * 16 + l4 * 4 + r;
        size_t col = (size_t)col0 + wn * 64 + nf * 16 + l15;
        store_c(C, row * (size_t)ldc + col, acc[mf][nf][r]);
      }
#undef STAGE_A
#undef STAGE_B
#undef MFMA_Q
}

// ---------------- 256x128 2-phase GEMM (tail-free partner for gemm1's K/V columns) ----------------
__global__ __launch_bounds__(512, 2) void gemm_bn128(const u16* __restrict__ A, const u16* __restrict__ B,
                                                     u16* __restrict__ C, int M, int N, int K, int ldc) {
  __shared__ __align__(16) u16 lds[49152];  // 96 KiB
  char* LB = (char*)lds;
  const int tid = threadIdx.x;
  const int w = tid >> 6, lane = tid & 63;
  const int l15 = lane & 15, l4 = lane >> 4;
  const int wm = w >> 2, wn = w & 3;

  int nwg = gridDim.x;
  int q = nwg >> 3, rr = nwg & 7;
  int xcd = blockIdx.x & 7, idx = blockIdx.x >> 3;
  int sw = (xcd < rr ? xcd * (q + 1) : rr * (q + 1) + (xcd - rr) * q) + idx;
  int gxn = N >> 7;
  int by = sw / gxn, bx = sw - by * gxn;
  const int row0 = by << 8, col0 = bx << 7;
  const int NT = K >> 6;

  const int srow = w * 8 + (lane >> 3);
  const int sc16 = (lane & 7) ^ ((lane >> 3) & 7);
  const u16* gA = A + (size_t)(row0 + srow) * K + sc16 * 8;
  const u16* gB = B + (size_t)(col0 + srow) * K + sc16 * 8;

  const int fl = (l15 & 7) << 4;
  const int aoff = (wm * 128 + l15) * 128 + l4 * 16;
  const int boff = (wn * 32 + l15) * 128 + l4 * 16;

  f32x4 acc[8][2] = {};
  bf16x8 fA[4][2], fB[2][2];

#define STAGE_A(kt, h, base)                                                      \
  {                                                                               \
    const u16* g_ = gA + (size_t)((h)*128) * K + (size_t)(kt)*64;                 \
    gload_lds16(g_, (base) + (h)*16384 + w * 1024);                               \
    gload_lds16(g_ + (size_t)64 * K, (base) + (h)*16384 + 8192 + w * 1024);       \
  }
#define STAGE_B(kt, base)                                                         \
  {                                                                               \
    const u16* g_ = gB + (size_t)(kt)*64;                                         \
    gload_lds16(g_, (base) + w * 1024);                                           \
    gload_lds16(g_ + (size_t)64 * K, (base) + 8192 + w * 1024);                   \
  }

  STAGE_A(0, 0, LB);
  STAGE_A(0, 1, LB);
  STAGE_B(0, LB + 65536);
  STAGE_A(1, 0, LB + 32768);
  STAGE_B(1, LB + 65536 + 16384);
  asm volatile("s_waitcnt vmcnt(4)" ::: "memory");
  SBAR();

  for (int t = 0; t < NT; ++t) {
    char* ac = LB + (t & 1) * 32768;
    char* bc = LB + 65536 + (t & 1) * 16384;
    char* an = LB + ((t + 1) & 1) * 32768;

    // ---- P1 ----
#pragma unroll
    for (int mf = 0; mf < 4; mf++)
#pragma unroll
      for (int kk = 0; kk < 2; kk++)
        fA[mf][kk] = *(const bf16x8*)(ac + ((aoff + mf * 2048 + kk * 64) ^ fl));
#pragma unroll
    for (int nf = 0; nf < 2; nf++)
#pragma unroll
      for (int kk = 0; kk < 2; kk++)
        fB[nf][kk] = *(const bf16x8*)(bc + ((boff + nf * 2048 + kk * 64) ^ fl));
    if (t + 1 < NT) STAGE_A(t + 1, 1, an);
    asm volatile("s_waitcnt lgkmcnt(8)" ::: "memory");
    SBAR();
    asm volatile("s_waitcnt lgkmcnt(0)" ::: "memory");
    __builtin_amdgcn_sched_barrier(0);
    __builtin_amdgcn_s_setprio(1);
#pragma unroll
    for (int kk = 0; kk < 2; kk++)
#pragma unroll
      for (int mf = 0; mf < 4; mf++)
#pragma unroll
        for (int nf = 0; nf < 2; nf++)
          acc[mf][nf] = __builtin_amdgcn_mfma_f32_16x16x32_bf16(fA[mf][kk], fB[nf][kk], acc[mf][nf], 0, 0, 0);
    __builtin_amdgcn_s_setprio(0);
    SBAR();

    // ---- P2 ----
#pragma unroll
    for (int mf = 0; mf < 4; mf++)
#pragma unroll
      for (int kk = 0; kk < 2; kk++)
        fA[mf][kk] = *(const bf16x8*)(ac + ((aoff + (mf + 4) * 2048 + kk * 64) ^ fl));
    if (t + 2 < NT) {
      STAGE_A(t + 2, 0, ac);
      STAGE_B(t + 2, bc);
    }
    SBAR();
    asm volatile("s_waitcnt lgkmcnt(0)" ::: "memory");
    __builtin_amdgcn_sched_barrier(0);
    __builtin_amdgcn_s_setprio(1);
#pragma unroll
    for (int kk = 0; kk < 2; kk++)
#pragma unroll
      for (int mf = 0; mf < 4; mf++)
#pragma unroll
        for (int nf = 0; nf < 2; nf++)
          acc[mf + 4][nf] = __builtin_amdgcn_mfma_f32_16x16x32_bf16(fA[mf][kk], fB[nf][kk], acc[mf + 4][nf], 0, 0, 0);
    __builtin_amdgcn_s_setprio(0);
    if (t <= NT - 3) {
      asm volatile("s_waitcnt vmcnt(4)" ::: "memory");
      SBAR();
    } else if (t < NT - 1) {
      asm volatile("s_waitcnt vmcnt(0)" ::: "memory");
      SBAR();
    }
  }

#pragma unroll
  for (int mf = 0; mf < 8; mf++)
#pragma unroll
    for (int nf = 0; nf < 2; nf++)
#pragma unroll
      for (int r = 0; r < 4; r++) {
        size_t row = (size_t)row0 + wm * 128 + mf * 16 + l4 * 4 + r;
        size_t col = (size_t)col0 + wn * 32 + nf * 16 + l15;
        C[row * (size_t)ldc + col] = f2bf(acc[mf][nf][r]);
      }
#undef STAGE_A
#undef STAGE_B
}

// ---------------- causal GQA flash attention v3: swapped QK^T + in-register softmax (T12) ----------------
// 4 waves x 32 q-rows. 32x32x16 MFMA. S^T = K*Q^T -> lane owns full P row for q = lane&31.
// P -> PV A-frag via 16 cvt_pk + 8 permlane32_swap per tile. No P LDS round-trip.
// K/V staging + swizzled images unchanged (Kt: row n, chunk c at c^(n&7); Vt: d-major, chunk^(d&7)).
__global__ __launch_bounds__(256, 2) void attn_fwd(const u16* __restrict__ qkv,
                                                   const u16* __restrict__ vtg,
                                                   u16* __restrict__ out) {
  constexpr int S = 2048, F = 6144, E = 4096;
  __shared__ __align__(16) u16 Kt[2 * 8192];
  __shared__ __align__(16) u16 Vt[2 * 8192];

  const int tid = threadIdx.x;
  const int w = tid >> 6, lane = tid & 63;
  const int l31 = lane & 31, hi = lane >> 5;
  const int pair = blockIdx.x;  // 0..7
  const int b = blockIdx.y >> 5, h = blockIdx.y & 31, kvh = h >> 2;
  const size_t rowB = (size_t)b * S;
  const float sc = 0.08838834764831845f * 1.4426950408889634f;  // 1/sqrt(128)*log2(e)
  const int sgn = tid >> 4, sgc = tid & 15;
  const size_t vtb = (size_t)(b * 8 + kvh) * 32 * 8192;

  auto stage = [&](int j, int buf) {
    char* kd = ((char*)Kt) + buf * 16384 + w * 1024;
    char* vd = ((char*)Vt) + buf * 16384 + w * 1024;
    const u16* vs = vtg + vtb + (size_t)j * 8192 + tid * 8;
#pragma unroll
    for (int p = 0; p < 4; p++) {
      int n = p * 16 + sgn;
      const u16* g = qkv + (rowB + j * 64 + n) * F + 4096 + kvh * 128 + (sgc ^ (n & 7)) * 8;
      gload_lds16(g, kd + p * 4096);
      gload_lds16(vs + p * 2048, vd + p * 4096);
    }
  };

  for (int half = 0; half < 2; ++half) {
    const int t = half ? 15 - pair : pair;
    const int nt = 2 * t + 2;
    const int r0 = t * 128;
    const int qg = r0 + w * 32 + l31;

    // Q frags (B-operand): lane holds Q[q=l31][d = 16*ds + hi*8 + e]
    bf16x8 qf[8];
    {
      const u16* qp = qkv + (rowB + qg) * F + h * 128 + hi * 8;
#pragma unroll
      for (int ds = 0; ds < 8; ds++) qf[ds] = *reinterpret_cast<const bf16x8*>(qp + ds * 16);
    }

    f32x16 acco[4] = {};  // [df]: col d=32df+l31, row q=(rg&3)+8*(rg>>2)+4hi
    float m = -1e30f, l = 0.f;

    stage(0, 0);
    __syncthreads();

    for (int j = 0; j < nt; ++j) {
      const int cur = j & 1;
      if (j + 1 < nt) stage(j + 1, cur ^ 1);

      // ---- S^T = K Q^T (A=K rows kv, B=Q cols q) ----
      const char* kbase = ((const char*)Kt) + cur * 16384;
      f32x16 s0 = {}, s1 = {};
      __builtin_amdgcn_s_setprio(1);
#pragma unroll
      for (int ds = 0; ds < 8; ds++) {
        int ch = ((2 * ds + hi) ^ (l31 & 7)) << 4;
        bf16x8 k0 = *reinterpret_cast<const bf16x8*>(kbase + l31 * 256 + ch);
        bf16x8 k1 = *reinterpret_cast<const bf16x8*>(kbase + (32 + l31) * 256 + ch);
        s0 = __builtin_amdgcn_mfma_f32_32x32x16_bf16(k0, qf[ds], s0, 0, 0, 0);
        s1 = __builtin_amdgcn_mfma_f32_32x32x16_bf16(k1, qf[ds], s1, 0, 0, 0);
      }
      __builtin_amdgcn_s_setprio(0);

      // ---- scale + causal mask ----
      f32x16 px0, px1;
      if (j >= 2 * t) {
#pragma unroll
        for (int rg = 0; rg < 16; rg++) {
          int kv0 = j * 64 + (rg & 3) + 8 * (rg >> 2) + 4 * hi;
          px0[rg] = (kv0 > qg) ? -1e30f : s0[rg] * sc;
          px1[rg] = (kv0 + 32 > qg) ? -1e30f : s1[rg] * sc;
        }
      } else {
#pragma unroll
        for (int rg = 0; rg < 16; rg++) {
          px0[rg] = s0[rg] * sc;
          px1[rg] = s1[rg] * sc;
        }
      }

      // ---- row max (in-register tree + one cross-half shuffle) ----
      float mt[8];
#pragma unroll
      for (int i = 0; i < 8; i++)
        mt[i] = fmaxf(fmaxf(px0[i], px0[i + 8]), fmaxf(px1[i], px1[i + 8]));
#pragma unroll
      for (int stp = 4; stp; stp >>= 1)
#pragma unroll
        for (int i = 0; i < stp; i++) mt[i] = fmaxf(mt[i], mt[i + stp]);
      float pm = fmaxf(mt[0], __shfl_xor(mt[0], 32));

      // ---- defer-max rescale (THR=8) ----
      if (__any(pm > m + 8.0f)) {
        float mn = fmaxf(m, pm);
        float fr = exp2f(m - mn);
        m = mn;
        l *= fr;
#pragma unroll
        for (int rg = 0; rg < 16; rg++) {
          int qrow = (rg & 3) + 8 * (rg >> 2) + 4 * hi;
          float frq = __builtin_bit_cast(
              float, __builtin_amdgcn_ds_bpermute(qrow << 2, __builtin_bit_cast(int, fr)));
          acco[0][rg] *= frq;
          acco[1][rg] *= frq;
          acco[2][rg] *= frq;
          acco[3][rg] *= frq;
        }
      }

      // ---- P = exp2(S - m), row sum ----
#pragma unroll
      for (int rg = 0; rg < 16; rg++) {
        px0[rg] = exp2f(px0[rg] - m);
        px1[rg] = exp2f(px1[rg] - m);
      }
      float at[8];
#pragma unroll
      for (int i = 0; i < 8; i++)
        at[i] = (px0[i] + px0[i + 8]) + (px1[i] + px1[i + 8]);
#pragma unroll
      for (int stp = 4; stp; stp >>= 1)
#pragma unroll
        for (int i = 0; i < stp; i++) at[i] += at[i + stp];
      l += at[0] + __shfl_xor(at[0], 32);

      // ---- O += P V : build PA frags in-register, 32x32x16 MFMA ----
      const char* vbase = ((const char*)Vt) + cur * 16384;
      __builtin_amdgcn_s_setprio(1);
#define PV_STEP(PH, SS)                                                               \
  {                                                                                   \
    uint32_t X0 = cvtpk(PH[((SS)&1) * 8 + 0], PH[((SS)&1) * 8 + 1]);                  \
    uint32_t Y0 = cvtpk(PH[((SS)&1) * 8 + 4], PH[((SS)&1) * 8 + 5]);                  \
    uint32_t X1 = cvtpk(PH[((SS)&1) * 8 + 2], PH[((SS)&1) * 8 + 3]);                  \
    uint32_t Y1 = cvtpk(PH[((SS)&1) * 8 + 6], PH[((SS)&1) * 8 + 7]);                  \
    plswap(X0, Y0);                                                                   \
    plswap(X1, Y1);                                                                   \
    u32x4 pw = {X0, X1, Y0, Y1};                                                      \
    bf16x8 pa = __builtin_bit_cast(bf16x8, pw);                                       \
    _Pragma("unroll") for (int df = 0; df < 4; df++) {                                \
      bf16x8 vf = *reinterpret_cast<const bf16x8*>(                                   \
          vbase + (32 * df + l31) * 128 + (((2 * (SS) + hi) ^ (l31 & 7)) << 4));      \
      acco[df] = __builtin_amdgcn_mfma_f32_32x32x16_bf16(pa, vf, acco[df], 0, 0, 0);  \
    }                                                                                 \
  }
      PV_STEP(px0, 0)
      PV_STEP(px0, 1)
      PV_STEP(px1, 2)
      PV_STEP(px1, 3)
#undef PV_STEP
      __builtin_amdgcn_s_setprio(0);

      __syncthreads();
    }

    // ---- epilogue: fetch 1/l per acco-row via bpermute, store ----
    float linv = 1.f / l;
#pragma unroll
    for (int rg = 0; rg < 16; rg++) {
      int qrow = (rg & 3) + 8 * (rg >> 2) + 4 * hi;
      float lv = __builtin_bit_cast(
          float, __builtin_amdgcn_ds_bpermute(qrow << 2, __builtin_bit_cast(int, linv)));
      size_t row = rowB + r0 + w * 32 + qrow;
      u16* op = out + row * E + h * 128 + l31;
#pragma unroll
      for (int df = 0; df < 4; df++) op[df * 32] = f2bf(acco[df][rg] * lv);
    }
  }
}

extern "C" void kernel_launch(void* const* d_in, const int* in_sizes, int n_in,
                              void* d_out, int out_size, void* d_ws, size_t ws_size,
                              hipStream_t stream) {
  const float* x = (const float*)d_in[0];
  const float* w_in = (const float*)d_in[1];
  const float* w_out = (const float*)d_in[2];
  float* out = (float*)d_out;
  char* ws = (char*)d_ws;

  u16* xb = (u16*)(ws);                                   // 33,554,432 B (reused as attn out)
  u16* wib = (u16*)(ws + 33554432ull);                    // 50,331,648 B (reused as V^T images)
  u16* wob = (u16*)(ws + 83886080ull);                    // 33,554,432 B
  u16* qkvb = (u16*)(ws + 117440512ull);                  // 50,331,648 B
  float* ct = (float*)(ws + 167772160ull);                // 524,288 B
  float* st = ct + 2048 * 64;                             // 524,288 B
  u16* attnb = xb;
  u16* vtg = wib;

  cvt_bf16<<<8192, 256, 0, stream>>>(x, xb, 16777216);
  cvt_bf16<<<12288, 256, 0, stream>>>(w_in, wib, 25165824);
  cvt_bf16<<<8192, 256, 0, stream>>>(w_out, wob, 16777216);
  rope_table<<<512, 256, 0, stream>>>(ct, st);
  gemm256<u16><<<256, 512, 0, stream>>>(xb, wib, qkvb, 4096, 4096, 4096, 6144);
  gemm_bn128<<<256, 512, 0, stream>>>(xb, wib + (size_t)4096 * 4096, qkvb + 4096, 4096, 2048, 4096, 6144);
  rope_apply<<<5120, 256, 0, stream>>>(qkvb, ct, st);
  prep_vt<<<512, 256, 0, stream>>>(qkvb, vtg);
  attn_fwd<<<dim3(8, 64), 256, 0, stream>>>(qkvb, vtg, attnb);
  gemm256<float><<<256, 512, 0, stream>>>(attnb, wob, out, 4096, 4096, 4096, 4096);
}

// Round 8
// 507.622 us; speedup vs baseline: 1.7874x; 1.0069x over previous
//
#include <hip/hip_runtime.h>
#include <hip/hip_bf16.h>
#include <stdint.h>

typedef unsigned short u16;
typedef __bf16 bf16x8 __attribute__((ext_vector_type(8)));
typedef u16 u16x8 __attribute__((ext_vector_type(8)));
typedef float f32x4 __attribute__((ext_vector_type(4)));
typedef float f32x16 __attribute__((ext_vector_type(16)));
typedef uint32_t u32x4 __attribute__((ext_vector_type(4)));

#define DEV __device__ __forceinline__
#define SBAR() asm volatile("s_barrier" ::: "memory")
#define SCHEDB() __builtin_amdgcn_sched_barrier(0)

DEV u16 f2bf(float f) {
  uint32_t u = __builtin_bit_cast(uint32_t, f);
  return (u16)((u + 0x7FFFu + ((u >> 16) & 1u)) >> 16);
}
DEV float bf2f(u16 h) { return __builtin_bit_cast(float, (uint32_t)h << 16); }

DEV void gload_lds16(const void* g, void* l) {
  __builtin_amdgcn_global_load_lds((const __attribute__((address_space(1))) uint32_t*)g,
                                   (__attribute__((address_space(3))) uint32_t*)l, 16, 0, 0);
}

DEV uint32_t cvtpk(float lo, float hi) {
  uint32_t r;
  asm("v_cvt_pk_bf16_f32 %0, %1, %2" : "=v"(r) : "v"(lo), "v"(hi));
  return r;
}
DEV void plswap(uint32_t& a, uint32_t& b) {
  asm("v_permlane32_swap_b32 %0, %1" : "+v"(a), "+v"(b));
}

// ---------------- elementwise f32 -> bf16 cast ----------------
__global__ void cvt_bf16(const float* __restrict__ in, u16* __restrict__ out, int n) {
  int i = (blockIdx.x * 256 + threadIdx.x) * 8;
  if (i >= n) return;
  const float4* p = reinterpret_cast<const float4*>(in + i);
  float4 a = p[0], b = p[1];
  u16x8 o;
  o[0] = f2bf(a.x); o[1] = f2bf(a.y); o[2] = f2bf(a.z); o[3] = f2bf(a.w);
  o[4] = f2bf(b.x); o[5] = f2bf(b.y); o[6] = f2bf(b.z); o[7] = f2bf(b.w);
  *reinterpret_cast<u16x8*>(out + i) = o;
}

// ---------------- RoPE cos/sin table (S=2048, 64 pairs) ----------------
__global__ void rope_table(float* __restrict__ ct, float* __restrict__ st) {
  int i = blockIdx.x * 256 + threadIdx.x;
  int s = i >> 6, d = i & 63;
  float invf = powf(10000.0f, -(float)d * (1.0f / 64.0f));
  float ang = (float)s * invf;
  ct[i] = cosf(ang);
  st[i] = sinf(ang);
}

// ---------------- RoPE applied in-place on bf16 qkv ----------------
__global__ void rope_apply(u16* __restrict__ qkv, const float* __restrict__ ct, const float* __restrict__ st) {
  int idx = blockIdx.x * 256 + threadIdx.x;
  int grp = idx & 7;
  int head = (idx >> 3) % 40;
  int row = idx / 320;
  int s = row & 2047;
  size_t f0 = head < 32 ? (size_t)head * 128 : (size_t)4096 + (size_t)(head - 32) * 128;
  u16* p = qkv + (size_t)row * 6144 + f0 + grp * 8;
  u16x8 a = *reinterpret_cast<const u16x8*>(p);
  u16x8 b = *reinterpret_cast<const u16x8*>(p + 64);
  const float4* cp = reinterpret_cast<const float4*>(ct + s * 64 + grp * 8);
  const float4* sp = reinterpret_cast<const float4*>(st + s * 64 + grp * 8);
  float4 c0 = cp[0], c1 = cp[1], s0 = sp[0], s1 = sp[1];
  float cc[8] = {c0.x, c0.y, c0.z, c0.w, c1.x, c1.y, c1.z, c1.w};
  float ss[8] = {s0.x, s0.y, s0.z, s0.w, s1.x, s1.y, s1.z, s1.w};
  u16x8 o1, o2;
#pragma unroll
  for (int i = 0; i < 8; i++) {
    float x1 = bf2f(a[i]), x2 = bf2f(b[i]);
    o1[i] = f2bf(x1 * cc[i] - x2 * ss[i]);
    o2[i] = f2bf(x2 * cc[i] + x1 * ss[i]);
  }
  *reinterpret_cast<u16x8*>(p) = o1;
  *reinterpret_cast<u16x8*>(p + 64) = o2;
}

// ---------------- V^T tile image prep ----------------
__global__ void prep_vt(const u16* __restrict__ qkv, u16* __restrict__ vtg) {
  int id = blockIdx.x;  // (b*8+kvh)*32 + j
  int j = id & 31, kvh = (id >> 5) & 7, b = id >> 8;
  const int tid = threadIdx.x;
  const size_t rowB = (size_t)b * 2048;
  u16* img = vtg + (size_t)id * 8192;
#pragma unroll
  for (int p = 0; p < 4; p++) {
    int lin = p * 256 + tid;
    int d = lin >> 3, c = lin & 7;
    const u16* src = qkv + (rowB + j * 64 + c * 8) * 6144 + 5120 + kvh * 128 + d;
    u16x8 v;
#pragma unroll
    for (int i = 0; i < 8; i++) v[i] = src[(size_t)i * 6144];
    *reinterpret_cast<u16x8*>(img + d * 64 + ((c ^ (d & 7)) << 3)) = v;
  }
}

// ---------------- GEMM epilogue store helpers ----------------
DEV void store_c(float* C, size_t idx, float v) { C[idx] = v; }
DEV void store_c(u16* C, size_t idx, float v) { C[idx] = f2bf(v); }

// ---------------- 256x256 GEMM, 2-barrier/K-tile schedule ----------------
// LDS: A buf0 [0,32K) buf1 [32K,64K); B buf0 [64K,96K) buf1 [96K,128K).
// Regions: A0 rows 0..127, A1 128..255; B0 cols 0..127, B1 128..255.
// Sync: mid-SBAR (all reads of tile t done) before stages into current bufs;
// boundary vmcnt(6)+SBAR (tile t+1 stages resident). MFMA gated only by counted lgkmcnt.
template <typename OutT>
__global__ __launch_bounds__(512, 2) void gemm256(const u16* __restrict__ A, const u16* __restrict__ B,
                                                  OutT* __restrict__ C, int M, int N, int K, int ldc) {
  __shared__ __align__(16) u16 lds[65536];  // 128 KiB
  char* LB = (char*)lds;
  const int tid = threadIdx.x;
  const int w = tid >> 6, lane = tid & 63;
  const int l15 = lane & 15, l4 = lane >> 4;
  const int wm = w >> 2, wn = w & 3;

  int nwg = gridDim.x;
  int q = nwg >> 3, rr = nwg & 7;
  int xcd = blockIdx.x & 7, idx = blockIdx.x >> 3;
  int sw = (xcd < rr ? xcd * (q + 1) : rr * (q + 1) + (xcd - rr) * q) + idx;
  int gxn = N >> 8;
  int by = sw / gxn, bx = sw - by * gxn;
  const int row0 = by << 8, col0 = bx << 8;
  const int NT = K >> 6;

  const int srow = w * 8 + (lane >> 3);
  const int sc16 = (lane & 7) ^ ((lane >> 3) & 7);
  const u16* gA = A + (size_t)(row0 + srow) * K + sc16 * 8;
  const u16* gB = B + (size_t)(col0 + srow) * K + sc16 * 8;

  const int fl = (l15 & 7) << 4;
  const int aoff = (wm * 128 + l15) * 128 + l4 * 16;
  const int boff = (wn * 64 + l15) * 128 + l4 * 16;

  f32x4 acc[8][4] = {};
  bf16x8 fA[4][2], fB0[2][2], fBc[2][2];

#define STAGE_A(kt, h, base)                                                      \
  {                                                                               \
    const u16* g_ = gA + (size_t)((h)*128) * K + (size_t)(kt)*64;                 \
    gload_lds16(g_, (base) + (h)*16384 + w * 1024);                               \
    gload_lds16(g_ + (size_t)64 * K, (base) + (h)*16384 + 8192 + w * 1024);       \
  }
#define STAGE_B(kt, h, base)                                                      \
  {                                                                               \
    const u16* g_ = gB + (size_t)((h)*128) * K + (size_t)(kt)*64;                 \
    gload_lds16(g_, (base) + (h)*16384 + w * 1024);                               \
    gload_lds16(g_ + (size_t)64 * K, (base) + (h)*16384 + 8192 + w * 1024);       \
  }
#define MFMA_Q(FB, MH, NH)                                                        \
  _Pragma("unroll") for (int kk = 0; kk < 2; kk++) {                              \
    _Pragma("unroll") for (int mf = 0; mf < 4; mf++) {                            \
      _Pragma("unroll") for (int nf = 0; nf < 2; nf++) {                          \
        acc[(MH)*4 + mf][(NH)*2 + nf] = __builtin_amdgcn_mfma_f32_16x16x32_bf16(  \
            fA[mf][kk], FB[nf][kk], acc[(MH)*4 + mf][(NH)*2 + nf], 0, 0, 0);      \
      }                                                                           \
    }                                                                             \
  }

  // prologue: tile0 {A0,A1,B0,B1} -> buf0; tile1 {A0,B0,B1} -> buf1 (A1(1) at t=0 start)
  STAGE_A(0, 0, LB);
  STAGE_A(0, 1, LB);
  STAGE_B(0, 0, LB + 65536);
  STAGE_B(0, 1, LB + 65536);
  STAGE_A(1, 0, LB + 32768);
  STAGE_B(1, 0, LB + 98304);
  STAGE_B(1, 1, LB + 98304);
  asm volatile("s_waitcnt vmcnt(6)" ::: "memory");
  SBAR();

  for (int t = 0; t < NT; ++t) {
    char* ac = LB + (t & 1) * 32768;
    char* bc = LB + 65536 + (t & 1) * 32768;
    char* an = LB + ((t + 1) & 1) * 32768;

    // stage A1(t+1) into other buffer (its region was last read in tile t-1)
    if (t + 1 < NT) STAGE_A(t + 1, 1, an);

    // ---- reads: fA-1st (8), fB0 (4), fBc (4) — group order pinned ----
#pragma unroll
    for (int mf = 0; mf < 4; mf++)
#pragma unroll
      for (int kk = 0; kk < 2; kk++)
        fA[mf][kk] = *(const bf16x8*)(ac + ((aoff + mf * 2048 + kk * 64) ^ fl));
    SCHEDB();
#pragma unroll
    for (int nf = 0; nf < 2; nf++)
#pragma unroll
      for (int kk = 0; kk < 2; kk++)
        fB0[nf][kk] = *(const bf16x8*)(bc + ((boff + nf * 2048 + kk * 64) ^ fl));
    SCHEDB();
#pragma unroll
    for (int nf = 0; nf < 2; nf++)
#pragma unroll
      for (int kk = 0; kk < 2; kk++)
        fBc[nf][kk] = *(const bf16x8*)(bc + ((boff + (nf + 2) * 2048 + kk * 64) ^ fl));
    SCHEDB();

    // ---- Q00: fA1st + fB0 ready (keep 4 newest = fBc outstanding) ----
    asm volatile("s_waitcnt lgkmcnt(4)" ::: "memory");
    SCHEDB();
    __builtin_amdgcn_s_setprio(1);
    MFMA_Q(fB0, 0, 0);
    __builtin_amdgcn_s_setprio(0);

    // ---- Q01: fBc ready ----
    asm volatile("s_waitcnt lgkmcnt(0)" ::: "memory");
    SCHEDB();
    __builtin_amdgcn_s_setprio(1);
    MFMA_Q(fBc, 0, 1);
    __builtin_amdgcn_s_setprio(0);

    // ---- reads: fA-2nd (8, reuse fA regs) ----
#pragma unroll
    for (int mf = 0; mf < 4; mf++)
#pragma unroll
      for (int kk = 0; kk < 2; kk++)
        fA[mf][kk] = *(const bf16x8*)(ac + ((aoff + (mf + 4) * 2048 + kk * 64) ^ fl));
    asm volatile("s_waitcnt lgkmcnt(0)" ::: "memory");
    SCHEDB();

    // ---- mid barrier: ALL waves' tile-t reads complete -> safe to overwrite ----
    SBAR();
    if (t + 2 < NT) {
      STAGE_B(t + 2, 0, bc);
      STAGE_B(t + 2, 1, bc);
      STAGE_A(t + 2, 0, ac);
    }
    __builtin_amdgcn_s_setprio(1);
    MFMA_Q(fBc, 1, 1);
    MFMA_Q(fB0, 1, 0);
    __builtin_amdgcn_s_setprio(0);

    // ---- boundary: keep 6 newest (t+2 mid-stages); everything for t+1 resident ----
    if (t + 2 < NT) {
      asm volatile("s_waitcnt vmcnt(6)" ::: "memory");
      SBAR();
    } else if (t + 1 < NT) {
      asm volatile("s_waitcnt vmcnt(0)" ::: "memory");
      SBAR();
    }
  }

#pragma unroll
  for (int mf = 0; mf < 8; mf++)
#pragma unroll
    for (int nf = 0; nf < 4; nf++)
#pragma unroll
      for (int r = 0; r < 4; r++) {
        size_t row = (size_t)row0 + wm * 128 + mf * 16 + l4 * 4 + r;
        size_t col = (size_t)col0 + wn * 64 + nf * 16 + l15;
        store_c(C, row * (size_t)ldc + col, acc[mf][nf][r]);
      }
#undef STAGE_A
#undef STAGE_B
#undef MFMA_Q
}

// ---------------- 256x128 GEMM, 2-barrier/K-tile (gemm1 K/V columns) ----------------
__global__ __launch_bounds__(512, 2) void gemm_bn128(const u16* __restrict__ A, const u16* __restrict__ B,
                                                     u16* __restrict__ C, int M, int N, int K, int ldc) {
  __shared__ __align__(16) u16 lds[49152];  // 96 KiB
  char* LB = (char*)lds;
  const int tid = threadIdx.x;
  const int w = tid >> 6, lane = tid & 63;
  const int l15 = lane & 15, l4 = lane >> 4;
  const int wm = w >> 2, wn = w & 3;

  int nwg = gridDim.x;
  int q = nwg >> 3, rr = nwg & 7;
  int xcd = blockIdx.x & 7, idx = blockIdx.x >> 3;
  int sw = (xcd < rr ? xcd * (q + 1) : rr * (q + 1) + (xcd - rr) * q) + idx;
  int gxn = N >> 7;
  int by = sw / gxn, bx = sw - by * gxn;
  const int row0 = by << 8, col0 = bx << 7;
  const int NT = K >> 6;

  const int srow = w * 8 + (lane >> 3);
  const int sc16 = (lane & 7) ^ ((lane >> 3) & 7);
  const u16* gA = A + (size_t)(row0 + srow) * K + sc16 * 8;
  const u16* gB = B + (size_t)(col0 + srow) * K + sc16 * 8;

  const int fl = (l15 & 7) << 4;
  const int aoff = (wm * 128 + l15) * 128 + l4 * 16;
  const int boff = (wn * 32 + l15) * 128 + l4 * 16;

  f32x4 acc[8][2] = {};
  bf16x8 fA[4][2], fB[2][2];

#define STAGE_A(kt, h, base)                                                      \
  {                                                                               \
    const u16* g_ = gA + (size_t)((h)*128) * K + (size_t)(kt)*64;                 \
    gload_lds16(g_, (base) + (h)*16384 + w * 1024);                               \
    gload_lds16(g_ + (size_t)64 * K, (base) + (h)*16384 + 8192 + w * 1024);       \
  }
#define STAGE_B(kt, base)                                                         \
  {                                                                               \
    const u16* g_ = gB + (size_t)(kt)*64;                                         \
    gload_lds16(g_, (base) + w * 1024);                                           \
    gload_lds16(g_ + (size_t)64 * K, (base) + 8192 + w * 1024);                   \
  }

  STAGE_A(0, 0, LB);
  STAGE_A(0, 1, LB);
  STAGE_B(0, LB + 65536);
  STAGE_A(1, 0, LB + 32768);
  STAGE_B(1, LB + 65536 + 16384);
  asm volatile("s_waitcnt vmcnt(4)" ::: "memory");
  SBAR();

  for (int t = 0; t < NT; ++t) {
    char* ac = LB + (t & 1) * 32768;
    char* bc = LB + 65536 + (t & 1) * 16384;
    char* an = LB + ((t + 1) & 1) * 32768;

    if (t + 1 < NT) STAGE_A(t + 1, 1, an);

    // ---- reads: fA-1st (8) + fB (4) ----
#pragma unroll
    for (int mf = 0; mf < 4; mf++)
#pragma unroll
      for (int kk = 0; kk < 2; kk++)
        fA[mf][kk] = *(const bf16x8*)(ac + ((aoff + mf * 2048 + kk * 64) ^ fl));
#pragma unroll
    for (int nf = 0; nf < 2; nf++)
#pragma unroll
      for (int kk = 0; kk < 2; kk++)
        fB[nf][kk] = *(const bf16x8*)(bc + ((boff + nf * 2048 + kk * 64) ^ fl));
    SCHEDB();
    asm volatile("s_waitcnt lgkmcnt(0)" ::: "memory");
    SCHEDB();
    __builtin_amdgcn_s_setprio(1);
#pragma unroll
    for (int kk = 0; kk < 2; kk++)
#pragma unroll
      for (int mf = 0; mf < 4; mf++)
#pragma unroll
        for (int nf = 0; nf < 2; nf++)
          acc[mf][nf] = __builtin_amdgcn_mfma_f32_16x16x32_bf16(fA[mf][kk], fB[nf][kk], acc[mf][nf], 0, 0, 0);
    __builtin_amdgcn_s_setprio(0);

    // ---- reads: fA-2nd (8) ----
#pragma unroll
    for (int mf = 0; mf < 4; mf++)
#pragma unroll
      for (int kk = 0; kk < 2; kk++)
        fA[mf][kk] = *(const bf16x8*)(ac + ((aoff + (mf + 4) * 2048 + kk * 64) ^ fl));
    asm volatile("s_waitcnt lgkmcnt(0)" ::: "memory");
    SCHEDB();

    SBAR();  // all reads done
    if (t + 2 < NT) {
      STAGE_A(t + 2, 0, ac);
      STAGE_B(t + 2, bc);
    }
    __builtin_amdgcn_s_setprio(1);
#pragma unroll
    for (int kk = 0; kk < 2; kk++)
#pragma unroll
      for (int mf = 0; mf < 4; mf++)
#pragma unroll
        for (int nf = 0; nf < 2; nf++)
          acc[mf + 4][nf] = __builtin_amdgcn_mfma_f32_16x16x32_bf16(fA[mf][kk], fB[nf][kk], acc[mf + 4][nf], 0, 0, 0);
    __builtin_amdgcn_s_setprio(0);

    if (t + 2 < NT) {
      asm volatile("s_waitcnt vmcnt(4)" ::: "memory");
      SBAR();
    } else if (t + 1 < NT) {
      asm volatile("s_waitcnt vmcnt(0)" ::: "memory");
      SBAR();
    }
  }

#pragma unroll
  for (int mf = 0; mf < 8; mf++)
#pragma unroll
    for (int nf = 0; nf < 2; nf++)
#pragma unroll
      for (int r = 0; r < 4; r++) {
        size_t row = (size_t)row0 + wm * 128 + mf * 16 + l4 * 4 + r;
        size_t col = (size_t)col0 + wn * 32 + nf * 16 + l15;
        C[row * (size_t)ldc + col] = f2bf(acc[mf][nf][r]);
      }
#undef STAGE_A
#undef STAGE_B
}

// ---------------- causal GQA flash attention v3 (unchanged, round-7 proven) ----------------
__global__ __launch_bounds__(256, 2) void attn_fwd(const u16* __restrict__ qkv,
                                                   const u16* __restrict__ vtg,
                                                   u16* __restrict__ out) {
  constexpr int S = 2048, F = 6144, E = 4096;
  __shared__ __align__(16) u16 Kt[2 * 8192];
  __shared__ __align__(16) u16 Vt[2 * 8192];

  const int tid = threadIdx.x;
  const int w = tid >> 6, lane = tid & 63;
  const int l31 = lane & 31, hi = lane >> 5;
  const int pair = blockIdx.x;  // 0..7
  const int b = blockIdx.y >> 5, h = blockIdx.y & 31, kvh = h >> 2;
  const size_t rowB = (size_t)b * S;
  const float sc = 0.08838834764831845f * 1.4426950408889634f;  // 1/sqrt(128)*log2(e)
  const int sgn = tid >> 4, sgc = tid & 15;
  const size_t vtb = (size_t)(b * 8 + kvh) * 32 * 8192;

  auto stage = [&](int j, int buf) {
    char* kd = ((char*)Kt) + buf * 16384 + w * 1024;
    char* vd = ((char*)Vt) + buf * 16384 + w * 1024;
    const u16* vs = vtg + vtb + (size_t)j * 8192 + tid * 8;
#pragma unroll
    for (int p = 0; p < 4; p++) {
      int n = p * 16 + sgn;
      const u16* g = qkv + (rowB + j * 64 + n) * F + 4096 + kvh * 128 + (sgc ^ (n & 7)) * 8;
      gload_lds16(g, kd + p * 4096);
      gload_lds16(vs + p * 2048, vd + p * 4096);
    }
  };

  for (int half = 0; half < 2; ++half) {
    const int t = half ? 15 - pair : pair;
    const int nt = 2 * t + 2;
    const int r0 = t * 128;
    const int qg = r0 + w * 32 + l31;

    bf16x8 qf[8];
    {
      const u16* qp = qkv + (rowB + qg) * F + h * 128 + hi * 8;
#pragma unroll
      for (int ds = 0; ds < 8; ds++) qf[ds] = *reinterpret_cast<const bf16x8*>(qp + ds * 16);
    }

    f32x16 acco[4] = {};
    float m = -1e30f, l = 0.f;

    stage(0, 0);
    __syncthreads();

    for (int j = 0; j < nt; ++j) {
      const int cur = j & 1;
      if (j + 1 < nt) stage(j + 1, cur ^ 1);

      const char* kbase = ((const char*)Kt) + cur * 16384;
      f32x16 s0 = {}, s1 = {};
      __builtin_amdgcn_s_setprio(1);
#pragma unroll
      for (int ds = 0; ds < 8; ds++) {
        int ch = ((2 * ds + hi) ^ (l31 & 7)) << 4;
        bf16x8 k0 = *reinterpret_cast<const bf16x8*>(kbase + l31 * 256 + ch);
        bf16x8 k1 = *reinterpret_cast<const bf16x8*>(kbase + (32 + l31) * 256 + ch);
        s0 = __builtin_amdgcn_mfma_f32_32x32x16_bf16(k0, qf[ds], s0, 0, 0, 0);
        s1 = __builtin_amdgcn_mfma_f32_32x32x16_bf16(k1, qf[ds], s1, 0, 0, 0);
      }
      __builtin_amdgcn_s_setprio(0);

      f32x16 px0, px1;
      if (j >= 2 * t) {
#pragma unroll
        for (int rg = 0; rg < 16; rg++) {
          int kv0 = j * 64 + (rg & 3) + 8 * (rg >> 2) + 4 * hi;
          px0[rg] = (kv0 > qg) ? -1e30f : s0[rg] * sc;
          px1[rg] = (kv0 + 32 > qg) ? -1e30f : s1[rg] * sc;
        }
      } else {
#pragma unroll
        for (int rg = 0; rg < 16; rg++) {
          px0[rg] = s0[rg] * sc;
          px1[rg] = s1[rg] * sc;
        }
      }

      float mt[8];
#pragma unroll
      for (int i = 0; i < 8; i++)
        mt[i] = fmaxf(fmaxf(px0[i], px0[i + 8]), fmaxf(px1[i], px1[i + 8]));
#pragma unroll
      for (int stp = 4; stp; stp >>= 1)
#pragma unroll
        for (int i = 0; i < stp; i++) mt[i] = fmaxf(mt[i], mt[i + stp]);
      float pm = fmaxf(mt[0], __shfl_xor(mt[0], 32));

      if (__any(pm > m + 8.0f)) {
        float mn = fmaxf(m, pm);
        float fr = exp2f(m - mn);
        m = mn;
        l *= fr;
#pragma unroll
        for (int rg = 0; rg < 16; rg++) {
          int qrow = (rg & 3) + 8 * (rg >> 2) + 4 * hi;
          float frq = __builtin_bit_cast(
              float, __builtin_amdgcn_ds_bpermute(qrow << 2, __builtin_bit_cast(int, fr)));
          acco[0][rg] *= frq;
          acco[1][rg] *= frq;
          acco[2][rg] *= frq;
          acco[3][rg] *= frq;
        }
      }

#pragma unroll
      for (int rg = 0; rg < 16; rg++) {
        px0[rg] = exp2f(px0[rg] - m);
        px1[rg] = exp2f(px1[rg] - m);
      }
      float at[8];
#pragma unroll
      for (int i = 0; i < 8; i++)
        at[i] = (px0[i] + px0[i + 8]) + (px1[i] + px1[i + 8]);
#pragma unroll
      for (int stp = 4; stp; stp >>= 1)
#pragma unroll
        for (int i = 0; i < stp; i++) at[i] += at[i + stp];
      l += at[0] + __shfl_xor(at[0], 32);

      const char* vbase = ((const char*)Vt) + cur * 16384;
      __builtin_amdgcn_s_setprio(1);
#define PV_STEP(PH, SS)                                                               \
  {                                                                                   \
    uint32_t X0 = cvtpk(PH[((SS)&1) * 8 + 0], PH[((SS)&1) * 8 + 1]);                  \
    uint32_t Y0 = cvtpk(PH[((SS)&1) * 8 + 4], PH[((SS)&1) * 8 + 5]);                  \
    uint32_t X1 = cvtpk(PH[((SS)&1) * 8 + 2], PH[((SS)&1) * 8 + 3]);                  \
    uint32_t Y1 = cvtpk(PH[((SS)&1) * 8 + 6], PH[((SS)&1) * 8 + 7]);                  \
    plswap(X0, Y0);                                                                   \
    plswap(X1, Y1);                                                                   \
    u32x4 pw = {X0, X1, Y0, Y1};                                                      \
    bf16x8 pa = __builtin_bit_cast(bf16x8, pw);                                       \
    _Pragma("unroll") for (int df = 0; df < 4; df++) {                                \
      bf16x8 vf = *reinterpret_cast<const bf16x8*>(                                   \
          vbase + (32 * df + l31) * 128 + (((2 * (SS) + hi) ^ (l31 & 7)) << 4));      \
      acco[df] = __builtin_amdgcn_mfma_f32_32x32x16_bf16(pa, vf, acco[df], 0, 0, 0);  \
    }                                                                                 \
  }
      PV_STEP(px0, 0)
      PV_STEP(px0, 1)
      PV_STEP(px1, 2)
      PV_STEP(px1, 3)
#undef PV_STEP
      __builtin_amdgcn_s_setprio(0);

      __syncthreads();
    }

    float linv = 1.f / l;
#pragma unroll
    for (int rg = 0; rg < 16; rg++) {
      int qrow = (rg & 3) + 8 * (rg >> 2) + 4 * hi;
      float lv = __builtin_bit_cast(
          float, __builtin_amdgcn_ds_bpermute(qrow << 2, __builtin_bit_cast(int, linv)));
      size_t row = rowB + r0 + w * 32 + qrow;
      u16* op = out + row * E + h * 128 + l31;
#pragma unroll
      for (int df = 0; df < 4; df++) op[df * 32] = f2bf(acco[df][rg] * lv);
    }
  }
}

extern "C" void kernel_launch(void* const* d_in, const int* in_sizes, int n_in,
                              void* d_out, int out_size, void* d_ws, size_t ws_size,
                              hipStream_t stream) {
  const float* x = (const float*)d_in[0];
  const float* w_in = (const float*)d_in[1];
  const float* w_out = (const float*)d_in[2];
  float* out = (float*)d_out;
  char* ws = (char*)d_ws;

  u16* xb = (u16*)(ws);                                   // 33,554,432 B (reused as attn out)
  u16* wib = (u16*)(ws + 33554432ull);                    // 50,331,648 B (reused as V^T images)
  u16* wob = (u16*)(ws + 83886080ull);                    // 33,554,432 B
  u16* qkvb = (u16*)(ws + 117440512ull);                  // 50,331,648 B
  float* ct = (float*)(ws + 167772160ull);                // 524,288 B
  float* st = ct + 2048 * 64;                             // 524,288 B
  u16* attnb = xb;
  u16* vtg = wib;

  cvt_bf16<<<8192, 256, 0, stream>>>(x, xb, 16777216);
  cvt_bf16<<<12288, 256, 0, stream>>>(w_in, wib, 25165824);
  cvt_bf16<<<8192, 256, 0, stream>>>(w_out, wob, 16777216);
  rope_table<<<512, 256, 0, stream>>>(ct, st);
  gemm256<u16><<<256, 512, 0, stream>>>(xb, wib, qkvb, 4096, 4096, 4096, 6144);
  gemm_bn128<<<256, 512, 0, stream>>>(xb, wib + (size_t)4096 * 4096, qkvb + 4096, 4096, 2048, 4096, 6144);
  rope_apply<<<5120, 256, 0, stream>>>(qkvb, ct, st);
  prep_vt<<<512, 256, 0, stream>>>(qkvb, vtg);
  attn_fwd<<<dim3(8, 64), 256, 0, stream>>>(qkvb, vtg, attnb);
  gemm256<float><<<256, 512, 0, stream>>>(attnb, wob, out, 4096, 4096, 4096, 4096);
}